// Round 6
// baseline (145.101 us; speedup 1.0000x reference)
//
#include <hip/hip_runtime.h>
#include <hip/hip_bf16.h>
#include <cstdint>

using bf16 = __hip_bfloat16;
typedef __attribute__((ext_vector_type(8))) short s8v;
typedef __attribute__((ext_vector_type(4))) float f32x4;

#define DEV static __device__ __forceinline__

DEV float b2f(unsigned short u) {
    union { float f; unsigned int i; } w; w.i = ((unsigned int)u) << 16; return w.f;
}
DEV unsigned short f2b(float x) {
    __hip_bfloat16 h = __float2bfloat16(x);
    return __builtin_bit_cast(unsigned short, h);
}
DEV float sigm(float x) { return 1.0f / (1.0f + __expf(-x)); }

DEV void gload16(const void* g, void* l) {
    __builtin_amdgcn_global_load_lds(
        (const __attribute__((address_space(1))) uint32_t*)g,
        (__attribute__((address_space(3))) uint32_t*)l, 16, 0, 0);
}

template<int N> DEV void waitvm() {
    static_assert(N == 0 || N == 6 || N == 8, "unsupported vmcnt");
    if constexpr (N == 0) asm volatile("s_waitcnt vmcnt(0)" ::: "memory");
    else if constexpr (N == 6) asm volatile("s_waitcnt vmcnt(6)" ::: "memory");
    else asm volatile("s_waitcnt vmcnt(8)" ::: "memory");
}

// ---------------------------------------------------------------------------
// bf16 GEMM, C = A (MxK row-major) * B^T (B NxK row-major). BMxBN tile,
// BK=64, 4 waves (2x2), wave-tile (BM/2)x(BN/2), 16x16x32 MFMA.
// 2-buffer LDS with COUNTED vmcnt (T4): prologue stages tiles 0,1; per iter
//   COMPUTE(t) ; s_barrier ; STAGE(t+2 into freed buf) ;
//   s_waitcnt vmcnt(LD) [stage(t+1) done, stage(t+2) in flight] ; s_barrier.
// Never vmcnt(0) in steady state. XOR swizzle (phys = logical ^ ((row&7)<<4))
// via inverse-swizzled global staging source (gload_lds dest linear).
// Epilogues:
//  0: bf16 out = sigmoid(acc); + masked row-sum partials (BM=BN=128 only)
//  1: bf16 out = mask[row] ? d[row]*(acc + Yres[row,col]) : 0      (agg)
//  2: bf16 out = relu(acc + bias[col])
//  3: bf16 out = acc + bias[col]
//  4: f32  out = (mask[row]&mask[col]) ? sigmoid(acc) : 0
// ---------------------------------------------------------------------------
template<int BM, int BN, int EPI>
__global__ __launch_bounds__(256)
void gemm_bt(const bf16* __restrict__ A, const bf16* __restrict__ B,
             void* __restrict__ C, const int M, const int N, const int K,
             const size_t sA, const size_t sB, const size_t sC,
             const bf16* __restrict__ Yres, const float* __restrict__ dval,
             const int* __restrict__ mask, const float* __restrict__ bias,
             float* __restrict__ part)
{
    constexpr int MR = BM / 32;
    constexpr int NR = BN / 32;
    constexpr int NA = BM / 32;             // A staging instrs per wave
    constexpr int NB = BN / 32;             // B staging instrs per wave
    constexpr int LD = NA + NB;             // loads in flight per stage
    constexpr int TILEB = (BM + BN) * 128;  // bytes per buffer
    __shared__ char smb[2 * TILEB];

    const int b = blockIdx.z;
    const char* Ab = (const char*)(A + (size_t)b * sA);
    const char* Bb = (const char*)(B + (size_t)b * sB);
    const int bm = blockIdx.x * BM;
    const int bn = blockIdx.y * BN;
    const int tid = threadIdx.x;
    const int lane = tid & 63;
    const int wv = tid >> 6;
    const int wr = wv >> 1, wc = wv & 1;
    const int fr = lane & 15, fq = lane >> 4;
    const size_t lda = (size_t)K * 2;

    constexpr int NMAX = (NA > NB) ? NA : NB;
    size_t aOff[NMAX], bOff[NMAX];
    int ldsO[NMAX];
#pragma unroll
    for (int i = 0; i < NMAX; ++i) {
        const int local = i * 4096 + wv * 1024;
        const int myOff = local + lane * 16;
        const int row = myOff >> 7;
        const int lc = (myOff & 127) ^ ((row & 7) << 4);
        ldsO[i] = local;
        aOff[i] = (size_t)(bm + row) * lda + lc;
        bOff[i] = (size_t)(bn + row) * lda + lc;
    }

    f32x4 acc[MR][NR];
#pragma unroll
    for (int m = 0; m < MR; ++m)
#pragma unroll
        for (int n = 0; n < NR; ++n)
            acc[m][n] = (f32x4){0.f, 0.f, 0.f, 0.f};

    auto STAGE = [&](int buf, size_t kt) {
        const size_t kb = kt * 128;
        char* base = smb + buf * TILEB;
#pragma unroll
        for (int i = 0; i < NA; ++i)
            gload16(Ab + aOff[i] + kb, base + ldsO[i]);
#pragma unroll
        for (int i = 0; i < NB; ++i)
            gload16(Bb + bOff[i] + kb, base + BM * 128 + ldsO[i]);
    };

    auto COMPUTE = [&](int buf) {
        const char* sA_ = smb + buf * TILEB;
        const char* sB_ = sA_ + BM * 128;
#pragma unroll
        for (int kk = 0; kk < 2; ++kk) {
            s8v af[MR], bfv[NR];
#pragma unroll
            for (int m = 0; m < MR; ++m) {
                const int r = wr * (BM / 2) + m * 16 + fr;
                const int pb = (r << 7) | ((kk * 64 + fq * 16) ^ ((r & 7) << 4));
                af[m] = *(const s8v*)(sA_ + pb);
            }
#pragma unroll
            for (int n = 0; n < NR; ++n) {
                const int r = wc * (BN / 2) + n * 16 + fr;
                const int pb = (r << 7) | ((kk * 64 + fq * 16) ^ ((r & 7) << 4));
                bfv[n] = *(const s8v*)(sB_ + pb);
            }
#pragma unroll
            for (int m = 0; m < MR; ++m)
#pragma unroll
                for (int n = 0; n < NR; ++n)
                    acc[m][n] = __builtin_amdgcn_mfma_f32_16x16x32_bf16(
                        af[m], bfv[n], acc[m][n], 0, 0, 0);
        }
    };

    const int NT = K >> 6;   // >= 4 for all call sites
    STAGE(0, 0);
    STAGE(1, 1);
    waitvm<LD>();                       // stage(0) done; stage(1) in flight
    __builtin_amdgcn_s_barrier();
    __builtin_amdgcn_sched_barrier(0);
    for (int t = 0; t < NT; ++t) {
        COMPUTE(t & 1);
        __builtin_amdgcn_s_barrier();   // all waves done reading buf(t&1)
        if (t + 2 < NT) {
            STAGE(t & 1, t + 2);        // refill freed buffer
            waitvm<LD>();               // stage(t+1) done; stage(t+2) flying
            __builtin_amdgcn_s_barrier();
            __builtin_amdgcn_sched_barrier(0);
        } else if (t + 1 < NT) {
            waitvm<0>();                // last tile: drain
            __builtin_amdgcn_s_barrier();
            __builtin_amdgcn_sched_barrier(0);
        }
    }

    // epilogue: C/D layout col = lane&15, row = (lane>>4)*4 + reg
    const int row0 = bm + wr * (BM / 2) + fq * 4;
    const int col0 = bn + wc * (BN / 2) + fr;

    if constexpr (EPI == 0) {
        int cm[NR];
#pragma unroll
        for (int n = 0; n < NR; ++n) cm[n] = mask[(size_t)b * N + col0 + n * 16];
#pragma unroll
        for (int m = 0; m < MR; ++m) {
            float rs[4] = {0.f, 0.f, 0.f, 0.f};
#pragma unroll
            for (int n = 0; n < NR; ++n) {
                const int col = col0 + n * 16;
#pragma unroll
                for (int r = 0; r < 4; ++r) {
                    const int row = row0 + m * 16 + r;
                    const float x = sigm(acc[m][n][r]);
                    ((bf16*)C)[(size_t)b * sC + (size_t)row * N + col] =
                        __float2bfloat16(x);
                    if (cm[n]) rs[r] += x;
                }
            }
#pragma unroll
            for (int off = 1; off < 16; off <<= 1)
#pragma unroll
                for (int r = 0; r < 4; ++r) rs[r] += __shfl_xor(rs[r], off);
            if (fr == 0) {
#pragma unroll
                for (int r = 0; r < 4; ++r)
                    part[((size_t)b * M + row0 + m * 16 + r) * 32 +
                         blockIdx.y * 2 + wc] = rs[r];
            }
        }
        return;
    }

#pragma unroll
    for (int m = 0; m < MR; ++m) {
#pragma unroll
        for (int n = 0; n < NR; ++n) {
            const int col = col0 + n * 16;
#pragma unroll
            for (int r = 0; r < 4; ++r) {
                const int row = row0 + m * 16 + r;
                const float x = acc[m][n][r];
                const size_t cidx = (size_t)b * sC + (size_t)row * N + col;
                if constexpr (EPI == 1) {
                    const float dn = dval[(size_t)b * M + row];
                    const int mn = mask[(size_t)b * M + row];
                    const float yv =
                        b2f(__builtin_bit_cast(unsigned short,
                            Yres[(size_t)b * M * N + (size_t)row * N + col]));
                    ((bf16*)C)[cidx] = __float2bfloat16(mn ? dn * (x + yv) : 0.0f);
                } else if constexpr (EPI == 2) {
                    ((bf16*)C)[cidx] = __float2bfloat16(fmaxf(x + bias[col], 0.0f));
                } else if constexpr (EPI == 3) {
                    ((bf16*)C)[cidx] = __float2bfloat16(x + bias[col]);
                } else {
                    const int mr = mask[(size_t)b * M + row];
                    const int mc = mask[(size_t)b * M + col];
                    ((float*)C)[cidx] = (mr & mc) ? sigm(x) : 0.0f;
                }
            }
        }
    }
}

// ---------------------------------------------------------------------------
// blocks [0,4096): row-normalize X -> Xn (bf16) + rnorm. One wave per row.
// blocks [4096,4352): transpose W1,W2 to bf16.
// ---------------------------------------------------------------------------
__global__ __launch_bounds__(256)
void xn_kernel(const float* __restrict__ X, bf16* __restrict__ Xn,
               float* __restrict__ rnorm,
               const float* __restrict__ W1, const float* __restrict__ W2,
               bf16* __restrict__ W1t, bf16* __restrict__ W2t)
{
    if (blockIdx.x >= 4096) {
        const int idx = (blockIdx.x - 4096) * 256 + threadIdx.x;
        const int h = idx & 255, d = idx >> 8;
        W1t[h * 256 + d] = __float2bfloat16(W1[idx]);
        W2t[h * 256 + d] = __float2bfloat16(W2[idx]);
        return;
    }
    const int lane = threadIdx.x & 63;
    const size_t row = (size_t)blockIdx.x * 4 + (threadIdx.x >> 6);
    const float4 v = *(const float4*)&X[row * 256 + lane * 4];
    float ss = v.x * v.x + v.y * v.y + v.z * v.z + v.w * v.w;
#pragma unroll
    for (int o = 32; o; o >>= 1) ss += __shfl_xor(ss, o);
    const float nrm = fmaxf(sqrtf(ss), 1e-12f);
    const float inv = 1.0f / nrm;
    ushort4 o4;
    o4.x = f2b(v.x * inv); o4.y = f2b(v.y * inv);
    o4.z = f2b(v.z * inv); o4.w = f2b(v.w * inv);
    *(ushort4*)&Xn[row * 256 + lane * 4] = o4;
    if (lane == 0) rnorm[row] = nrm;
}

// ---------------------------------------------------------------------------
// Fused degree-finalize + Y/Yt build. Per block: 64 rows x 64 cols of Xn.
// ---------------------------------------------------------------------------
__global__ __launch_bounds__(256)
void ytY_kernel(const bf16* __restrict__ Xn, const float* __restrict__ rnorm,
                const float* __restrict__ part, const int* __restrict__ mask,
                float* __restrict__ dvl, bf16* __restrict__ Y,
                bf16* __restrict__ Yt)
{
    __shared__ float tile[64][65];
    __shared__ float dsh[64];
    const int b = blockIdx.z;
    const int m0 = blockIdx.x * 64, d0 = blockIdx.y * 64;
    const int t = threadIdx.x;

    if (t < 64) {
        const size_t grow = (size_t)b * 2048 + m0 + t;
        float s = 0.f;
#pragma unroll 8
        for (int i = 0; i < 32; ++i) s += part[grow * 32 + i];
        const float deg = mask[grow] ? (s + 1.0f) : 0.0f;
        const float dv = rsqrtf(fmaxf(deg, 1e-6f));
        dvl[grow] = dv;
        dsh[t] = mask[grow] ? dv * rnorm[grow] : 0.0f;
    }
    __syncthreads();

    const bf16* Xb = Xn + (size_t)b * 2048 * 256;
    const int rr = t >> 3;
    const int c8 = (t & 7) * 8;
#pragma unroll
    for (int i = 0; i < 2; ++i) {
        const int m = rr + i * 32;
        const int gm = m0 + m;
        const float s = dsh[m];
        const s8v v = *(const s8v*)&Xb[(size_t)gm * 256 + d0 + c8];
        ushort4 lo, hi;
        float f[8];
#pragma unroll
        for (int j = 0; j < 8; ++j) {
            f[j] = b2f((unsigned short)v[j]) * s;
            tile[m][c8 + j] = f[j];
        }
        lo.x = f2b(f[0]); lo.y = f2b(f[1]); lo.z = f2b(f[2]); lo.w = f2b(f[3]);
        hi.x = f2b(f[4]); hi.y = f2b(f[5]); hi.z = f2b(f[6]); hi.w = f2b(f[7]);
        bf16* yrow = Y + (size_t)b * 2048 * 256 + (size_t)gm * 256 + d0 + c8;
        *(ushort4*)yrow = lo;
        *(ushort4*)(yrow + 4) = hi;
    }
    __syncthreads();
    bf16* Yb = Yt + (size_t)b * 256 * 2048;
    const int dd = t >> 3;
    const int m8 = (t & 7) * 8;
#pragma unroll
    for (int i = 0; i < 2; ++i) {
        const int d = dd + i * 32;
        ushort4 lo, hi;
        lo.x = f2b(tile[m8 + 0][d]); lo.y = f2b(tile[m8 + 1][d]);
        lo.z = f2b(tile[m8 + 2][d]); lo.w = f2b(tile[m8 + 3][d]);
        hi.x = f2b(tile[m8 + 4][d]); hi.y = f2b(tile[m8 + 5][d]);
        hi.z = f2b(tile[m8 + 6][d]); hi.w = f2b(tile[m8 + 7][d]);
        bf16* yt = Yb + (size_t)(d0 + d) * 2048 + m0 + m8;
        *(ushort4*)yt = lo;
        *(ushort4*)(yt + 4) = hi;
    }
}

extern "C" void kernel_launch(void* const* d_in, const int* in_sizes, int n_in,
                              void* d_out, int out_size, void* d_ws, size_t ws_size,
                              hipStream_t stream)
{
    (void)in_sizes; (void)n_in; (void)out_size; (void)ws_size;
    const float* X  = (const float*)d_in[0];
    const int*  msk = (const int*)d_in[1];
    const float* W1 = (const float*)d_in[2];
    const float* b1 = (const float*)d_in[3];
    const float* W2 = (const float*)d_in[4];
    const float* b2 = (const float*)d_in[5];

    // scratch inside d_out (134,217,728 B), all dead before the final GEMM:
    char* O = (char*)d_out;
    bf16* S    = (bf16*)(O);                 // 67,108,864 B  [8][2048][2048]
    bf16* Xn   = (bf16*)(O + 67108864);      //  8,388,608 B  [8][2048][256]
    bf16* Yt   = (bf16*)(O + 75497472);      //  8,388,608 B  [8][256][2048]
    bf16* agg  = (bf16*)(O + 83886080);      //  8,388,608 B  [8][2048][256]
    bf16* Hf   = (bf16*)(O + 92274688);      //  8,388,608 B  [16384][256]
    float* dvl = (float*)(O + 100663296);    //     65,536 B  [8][2048]
    bf16* W1t  = (bf16*)(O + 100728832);     //    131,072 B
    bf16* W2t  = (bf16*)(O + 100859904);     //    131,072 B
    float* part= (float*)(O + 100990976);    //  2,097,152 B  [8][2048][32]
    bf16* Y    = (bf16*)(O + 103088128);     //  8,388,608 B  [8][2048][256]
    float* rnm = (float*)(O + 111476736);    //     65,536 B  [8][2048]
    bf16* P    = (bf16*)d_ws;                //  8,388,608 B  (survives final GEMM)

    xn_kernel<<<4352, 256, 0, stream>>>(X, Xn, rnm, W1, W2, W1t, W2t);

    // S = sigmoid(Xn Xn^T) bf16, + fused masked row-sum partials
    gemm_bt<128, 128, 0><<<dim3(16, 16, 8), 256, 0, stream>>>(
        Xn, Xn, S, 2048, 2048, 256,
        (size_t)2048 * 256, (size_t)2048 * 256, (size_t)2048 * 2048,
        nullptr, nullptr, msk, nullptr, part);

    // fused fin_deg + Y/Yt build
    ytY_kernel<<<dim3(32, 4, 8), 256, 0, stream>>>(
        Xn, rnm, part, msk, dvl, Y, Yt);

    // agg = m_i ? d_i*(S@Y + Y_i) : 0, bf16  (128x64 tile -> 512 blocks)
    gemm_bt<128, 64, 1><<<dim3(16, 4, 8), 256, 0, stream>>>(
        S, Yt, agg, 2048, 256, 2048,
        (size_t)2048 * 2048, (size_t)256 * 2048, (size_t)2048 * 256,
        Y, dvl, msk, nullptr, nullptr);

    // Hf = relu(agg @ W1 + b1)   (64x128 tile -> 512 blocks)
    gemm_bt<64, 128, 2><<<dim3(256, 2, 1), 256, 0, stream>>>(
        agg, W1t, Hf, 16384, 256, 256, 0, 0, 0,
        nullptr, nullptr, nullptr, b1, nullptr);

    // P = Hf @ W2 + b2
    gemm_bt<64, 128, 3><<<dim3(256, 2, 1), 256, 0, stream>>>(
        Hf, W2t, P, 16384, 256, 256, 0, 0, 0,
        nullptr, nullptr, nullptr, b2, nullptr);

    // out = mask_r * mask_c * sigmoid(P P^T), f32
    gemm_bt<128, 128, 4><<<dim3(16, 16, 8), 256, 0, stream>>>(
        P, P, d_out, 2048, 2048, 256,
        (size_t)2048 * 256, (size_t)2048 * 256, (size_t)2048 * 2048,
        nullptr, nullptr, msk, nullptr, nullptr);
}

// Round 7
// 130.587 us; speedup vs baseline: 1.1111x; 1.1111x over previous
//
#include <hip/hip_runtime.h>
#include <hip/hip_bf16.h>
#include <cstdint>

using bf16 = __hip_bfloat16;
typedef __attribute__((ext_vector_type(8))) short s8v;
typedef __attribute__((ext_vector_type(4))) float f32x4;

#define DEV static __device__ __forceinline__

DEV float b2f(unsigned short u) {
    union { float f; unsigned int i; } w; w.i = ((unsigned int)u) << 16; return w.f;
}
DEV unsigned short f2b(float x) {
    __hip_bfloat16 h = __float2bfloat16(x);
    return __builtin_bit_cast(unsigned short, h);
}
DEV float sigm(float x) { return 1.0f / (1.0f + __expf(-x)); }

DEV void gload16(const void* g, void* l) {
    __builtin_amdgcn_global_load_lds(
        (const __attribute__((address_space(1))) uint32_t*)g,
        (__attribute__((address_space(3))) uint32_t*)l, 16, 0, 0);
}

// ---------------------------------------------------------------------------
// bf16 GEMM, C = A (MxK row-major) * B^T (B NxK row-major). BMxBN tile,
// BK=64, 4 waves (2x2), 16x16x32 MFMA, 2-phase dbuf LDS (R5-proven loop),
// XOR swizzle (phys = logical ^ ((row&7)<<4)) via inverse-swizzled global
// staging source. 1-D grid + bijective XCD chunk swizzle (T1): block id ->
// (y fastest, then x, then batch), so each XCD owns a contiguous chunk
// (for agg: exactly one batch -> S[b] streamed once per XCD).
// Epilogues:
//  0: bf16 out = sigmoid(acc); + masked row-sum partials (BM=BN=128 only)
//  1: bf16 out = mask[row] ? d[row]*(acc + Yres[row,col]) : 0      (agg)
//  2: bf16 out = relu(acc + bias[col])
//  3: bf16 out = acc + bias[col]
// ---------------------------------------------------------------------------
template<int BM, int BN, int EPI>
__global__ __launch_bounds__(256)
void gemm_bt(const bf16* __restrict__ A, const bf16* __restrict__ B,
             void* __restrict__ C, const int M, const int N, const int K,
             const size_t sA, const size_t sB, const size_t sC,
             const bf16* __restrict__ Yres, const float* __restrict__ dval,
             const int* __restrict__ mask, const float* __restrict__ bias,
             float* __restrict__ part, const int GX, const int GY)
{
    constexpr int MR = BM / 32;
    constexpr int NR = BN / 32;
    constexpr int NA = BM / 32;
    constexpr int NB = BN / 32;
    constexpr int TILEB = (BM + BN) * 128;
    __shared__ char smb[2 * TILEB];

    // bijective XCD swizzle (gridDim.x % 8 == 0 at every call site)
    const int nblk = gridDim.x;
    const int q = nblk >> 3;
    const int id = blockIdx.x;
    const int swz = (id & 7) * q + (id >> 3);
    const int gy = swz % GY;
    const int xz = swz / GY;
    const int gx = xz % GX;
    const int b = xz / GX;

    const char* Ab = (const char*)(A + (size_t)b * sA);
    const char* Bb = (const char*)(B + (size_t)b * sB);
    const int bm = gx * BM;
    const int bn = gy * BN;
    const int tid = threadIdx.x;
    const int lane = tid & 63;
    const int wv = tid >> 6;
    const int wr = wv >> 1, wc = wv & 1;
    const int fr = lane & 15, fq = lane >> 4;
    const size_t lda = (size_t)K * 2;

    constexpr int NMAX = (NA > NB) ? NA : NB;
    size_t aOff[NMAX], bOff[NMAX];
    int ldsO[NMAX];
#pragma unroll
    for (int i = 0; i < NMAX; ++i) {
        const int local = i * 4096 + wv * 1024;
        const int myOff = local + lane * 16;
        const int row = myOff >> 7;
        const int lc = (myOff & 127) ^ ((row & 7) << 4);
        ldsO[i] = local;
        aOff[i] = (size_t)(bm + row) * lda + lc;
        bOff[i] = (size_t)(bn + row) * lda + lc;
    }

    f32x4 acc[MR][NR];
#pragma unroll
    for (int m = 0; m < MR; ++m)
#pragma unroll
        for (int n = 0; n < NR; ++n)
            acc[m][n] = (f32x4){0.f, 0.f, 0.f, 0.f};

    auto STAGE = [&](int buf, size_t kb) {
        char* base = smb + buf * TILEB;
#pragma unroll
        for (int i = 0; i < NA; ++i)
            gload16(Ab + aOff[i] + kb, base + ldsO[i]);
#pragma unroll
        for (int i = 0; i < NB; ++i)
            gload16(Bb + bOff[i] + kb, base + BM * 128 + ldsO[i]);
    };

    auto COMPUTE = [&](int buf) {
        const char* sA_ = smb + buf * TILEB;
        const char* sB_ = sA_ + BM * 128;
#pragma unroll
        for (int kk = 0; kk < 2; ++kk) {
            s8v af[MR], bfv[NR];
#pragma unroll
            for (int m = 0; m < MR; ++m) {
                const int r = wr * (BM / 2) + m * 16 + fr;
                const int pb = (r << 7) | ((kk * 64 + fq * 16) ^ ((r & 7) << 4));
                af[m] = *(const s8v*)(sA_ + pb);
            }
#pragma unroll
            for (int n = 0; n < NR; ++n) {
                const int r = wc * (BN / 2) + n * 16 + fr;
                const int pb = (r << 7) | ((kk * 64 + fq * 16) ^ ((r & 7) << 4));
                bfv[n] = *(const s8v*)(sB_ + pb);
            }
#pragma unroll
            for (int m = 0; m < MR; ++m)
#pragma unroll
                for (int n = 0; n < NR; ++n)
                    acc[m][n] = __builtin_amdgcn_mfma_f32_16x16x32_bf16(
                        af[m], bfv[n], acc[m][n], 0, 0, 0);
        }
    };

    const int NT = K >> 6;
    STAGE(0, 0);
    asm volatile("s_waitcnt vmcnt(0)" ::: "memory");
    __syncthreads();
    int cur = 0;
    for (int t = 0; t < NT - 1; ++t) {
        STAGE(cur ^ 1, (size_t)(t + 1) * 128);
        COMPUTE(cur);
        asm volatile("s_waitcnt vmcnt(0)" ::: "memory");
        __syncthreads();
        cur ^= 1;
    }
    COMPUTE(cur);

    // epilogue: C/D layout col = lane&15, row = (lane>>4)*4 + reg
    const int row0 = bm + wr * (BM / 2) + fq * 4;
    const int col0 = bn + wc * (BN / 2) + fr;

    if constexpr (EPI == 0) {
        int cm[NR];
#pragma unroll
        for (int n = 0; n < NR; ++n) cm[n] = mask[(size_t)b * N + col0 + n * 16];
#pragma unroll
        for (int m = 0; m < MR; ++m) {
            float rs[4] = {0.f, 0.f, 0.f, 0.f};
#pragma unroll
            for (int n = 0; n < NR; ++n) {
                const int col = col0 + n * 16;
#pragma unroll
                for (int r = 0; r < 4; ++r) {
                    const int row = row0 + m * 16 + r;
                    const float x = sigm(acc[m][n][r]);
                    ((bf16*)C)[(size_t)b * sC + (size_t)row * N + col] =
                        __float2bfloat16(x);
                    if (cm[n]) rs[r] += x;
                }
            }
#pragma unroll
            for (int off = 1; off < 16; off <<= 1)
#pragma unroll
                for (int r = 0; r < 4; ++r) rs[r] += __shfl_xor(rs[r], off);
            if (fr == 0) {
#pragma unroll
                for (int r = 0; r < 4; ++r)
                    part[((size_t)b * M + row0 + m * 16 + r) * 32 +
                         gy * 2 + wc] = rs[r];
            }
        }
        return;
    }

#pragma unroll
    for (int m = 0; m < MR; ++m) {
#pragma unroll
        for (int n = 0; n < NR; ++n) {
            const int col = col0 + n * 16;
#pragma unroll
            for (int r = 0; r < 4; ++r) {
                const int row = row0 + m * 16 + r;
                const float x = acc[m][n][r];
                const size_t cidx = (size_t)b * sC + (size_t)row * N + col;
                if constexpr (EPI == 1) {
                    const float dn = dval[(size_t)b * M + row];
                    const int mn = mask[(size_t)b * M + row];
                    const float yv =
                        b2f(__builtin_bit_cast(unsigned short,
                            Yres[(size_t)b * M * N + (size_t)row * N + col]));
                    ((bf16*)C)[cidx] = __float2bfloat16(mn ? dn * (x + yv) : 0.0f);
                } else if constexpr (EPI == 2) {
                    ((bf16*)C)[cidx] = __float2bfloat16(fmaxf(x + bias[col], 0.0f));
                } else {
                    ((bf16*)C)[cidx] = __float2bfloat16(x + bias[col]);
                }
            }
        }
    }
}

// ---------------------------------------------------------------------------
// Final symmetric GEMM: out[b] = pairmask(sigmoid(P P^T)), f32, computed on
// the upper triangle of 128x128 tiles only (136 tiles/batch). Off-diagonal
// blocks also emit the transposed tile via an LDS f32 buffer (quad-XOR
// swizzled) with coalesced writes. Grid = 8*136 = 1088, XCD chunk = 1 batch.
// ---------------------------------------------------------------------------
__global__ __launch_bounds__(256)
void gemm_tri(const bf16* __restrict__ Pm, float* __restrict__ C,
              const int* __restrict__ mask)
{
    constexpr int K = 256, N = 2048;
    constexpr int TILEB = 256 * 128;       // 32 KB per buffer
    __shared__ char smb[2 * TILEB];        // 64 KB; reused as f32 tile later

    const int id = blockIdx.x;
    const int swz = (id & 7) * 136 + (id >> 3);
    const int b = swz / 136;
    const int tri = swz - b * 136;
    int yb = (int)((sqrtf(8.0f * (float)tri + 1.0f) - 1.0f) * 0.5f);
    while ((yb + 1) * (yb + 2) / 2 <= tri) ++yb;
    while (yb * (yb + 1) / 2 > tri) --yb;
    const int xb = tri - yb * (yb + 1) / 2;   // xb <= yb
    const int bm = xb * 128, bn = yb * 128;

    const char* Ab = (const char*)(Pm + (size_t)b * N * K);
    const int tid = threadIdx.x;
    const int lane = tid & 63;
    const int wv = tid >> 6;
    const int wr = wv >> 1, wc = wv & 1;
    const int fr = lane & 15, fq = lane >> 4;
    const size_t lda = (size_t)K * 2;

    size_t aOff[4], bOff[4];
    int ldsO[4];
#pragma unroll
    for (int i = 0; i < 4; ++i) {
        const int local = i * 4096 + wv * 1024;
        const int myOff = local + lane * 16;
        const int row = myOff >> 7;
        const int lc = (myOff & 127) ^ ((row & 7) << 4);
        ldsO[i] = local;
        aOff[i] = (size_t)(bm + row) * lda + lc;
        bOff[i] = (size_t)(bn + row) * lda + lc;
    }

    f32x4 acc[4][4];
#pragma unroll
    for (int m = 0; m < 4; ++m)
#pragma unroll
        for (int n = 0; n < 4; ++n)
            acc[m][n] = (f32x4){0.f, 0.f, 0.f, 0.f};

    auto STAGE = [&](int buf, size_t kb) {
        char* base = smb + buf * TILEB;
#pragma unroll
        for (int i = 0; i < 4; ++i) {
            gload16(Ab + aOff[i] + kb, base + ldsO[i]);
            gload16(Ab + bOff[i] + kb, base + 16384 + ldsO[i]);
        }
    };

    auto COMPUTE = [&](int buf) {
        const char* sA_ = smb + buf * TILEB;
        const char* sB_ = sA_ + 16384;
#pragma unroll
        for (int kk = 0; kk < 2; ++kk) {
            s8v af[4], bfv[4];
#pragma unroll
            for (int m = 0; m < 4; ++m) {
                const int r = wr * 64 + m * 16 + fr;
                const int pb = (r << 7) | ((kk * 64 + fq * 16) ^ ((r & 7) << 4));
                af[m] = *(const s8v*)(sA_ + pb);
            }
#pragma unroll
            for (int n = 0; n < 4; ++n) {
                const int r = wc * 64 + n * 16 + fr;
                const int pb = (r << 7) | ((kk * 64 + fq * 16) ^ ((r & 7) << 4));
                bfv[n] = *(const s8v*)(sB_ + pb);
            }
#pragma unroll
            for (int m = 0; m < 4; ++m)
#pragma unroll
                for (int n = 0; n < 4; ++n)
                    acc[m][n] = __builtin_amdgcn_mfma_f32_16x16x32_bf16(
                        af[m], bfv[n], acc[m][n], 0, 0, 0);
        }
    };

    STAGE(0, 0);
    asm volatile("s_waitcnt vmcnt(0)" ::: "memory");
    __syncthreads();
    int cur = 0;
    for (int t = 0; t < 3; ++t) {
        STAGE(cur ^ 1, (size_t)(t + 1) * 128);
        COMPUTE(cur);
        asm volatile("s_waitcnt vmcnt(0)" ::: "memory");
        __syncthreads();
        cur ^= 1;
    }
    COMPUTE(cur);
    __syncthreads();   // all waves done with staging LDS before f32 reuse

    const int row0L = wr * 64 + fq * 4;    // local row base 0..124
    const int col0L = wc * 64 + fr;        // local col base 0..127
    const bool diag = (xb == yb);
    float4* ft = (float4*)smb;             // [colL][32 quads] f32x4, 64 KB

    int cmv[4];
#pragma unroll
    for (int n = 0; n < 4; ++n)
        cmv[n] = mask[(size_t)b * N + bn + col0L + n * 16];
#pragma unroll
    for (int m = 0; m < 4; ++m) {
        int rmv[4];
#pragma unroll
        for (int r = 0; r < 4; ++r)
            rmv[r] = mask[(size_t)b * N + bm + row0L + m * 16 + r];
#pragma unroll
        for (int n = 0; n < 4; ++n) {
            float vv[4];
#pragma unroll
            for (int r = 0; r < 4; ++r)
                vv[r] = (rmv[r] & cmv[n]) ? sigm(acc[m][n][r]) : 0.0f;
            // direct write: rows bm panel, cols bn panel
#pragma unroll
            for (int r = 0; r < 4; ++r)
                C[(size_t)b * N * N +
                  (size_t)(bm + row0L + m * 16 + r) * N + bn + col0L + n * 16] = vv[r];
            // stage transposed copy in LDS (quad-XOR swizzle)
            const int colL = col0L + n * 16;
            const int qd = (row0L + m * 16) >> 2;   // 0..31
            ft[colL * 32 + (qd ^ (colL & 31))] =
                make_float4(vv[0], vv[1], vv[2], vv[3]);
        }
    }
    if (!diag) {
        __syncthreads();
        // write transposed tile: rows bn panel, cols bm panel
#pragma unroll 4
        for (int it = 0; it < 16; ++it) {
            const int cL = it * 8 + (tid >> 5);     // 0..127
            const int qd = tid & 31;
            const float4 v4 = ft[cL * 32 + (qd ^ (cL & 31))];
            *(float4*)&C[(size_t)b * N * N +
                         (size_t)(bn + cL) * N + bm + qd * 4] = v4;
        }
    }
}

// ---------------------------------------------------------------------------
// blocks [0,4096): row-normalize X -> Xn (bf16) + rnorm. One wave per row.
// blocks [4096,4352): transpose W1,W2 to bf16.
// ---------------------------------------------------------------------------
__global__ __launch_bounds__(256)
void xn_kernel(const float* __restrict__ X, bf16* __restrict__ Xn,
               float* __restrict__ rnorm,
               const float* __restrict__ W1, const float* __restrict__ W2,
               bf16* __restrict__ W1t, bf16* __restrict__ W2t)
{
    if (blockIdx.x >= 4096) {
        const int idx = (blockIdx.x - 4096) * 256 + threadIdx.x;
        const int h = idx & 255, d = idx >> 8;
        W1t[h * 256 + d] = __float2bfloat16(W1[idx]);
        W2t[h * 256 + d] = __float2bfloat16(W2[idx]);
        return;
    }
    const int lane = threadIdx.x & 63;
    const size_t row = (size_t)blockIdx.x * 4 + (threadIdx.x >> 6);
    const float4 v = *(const float4*)&X[row * 256 + lane * 4];
    float ss = v.x * v.x + v.y * v.y + v.z * v.z + v.w * v.w;
#pragma unroll
    for (int o = 32; o; o >>= 1) ss += __shfl_xor(ss, o);
    const float nrm = fmaxf(sqrtf(ss), 1e-12f);
    const float inv = 1.0f / nrm;
    ushort4 o4;
    o4.x = f2b(v.x * inv); o4.y = f2b(v.y * inv);
    o4.z = f2b(v.z * inv); o4.w = f2b(v.w * inv);
    *(ushort4*)&Xn[row * 256 + lane * 4] = o4;
    if (lane == 0) rnorm[row] = nrm;
}

// ---------------------------------------------------------------------------
// Fused degree-finalize + Y/Yt build. Per block: 64 rows x 64 cols of Xn.
// ---------------------------------------------------------------------------
__global__ __launch_bounds__(256)
void ytY_kernel(const bf16* __restrict__ Xn, const float* __restrict__ rnorm,
                const float* __restrict__ part, const int* __restrict__ mask,
                float* __restrict__ dvl, bf16* __restrict__ Y,
                bf16* __restrict__ Yt)
{
    __shared__ float tile[64][65];
    __shared__ float dsh[64];
    const int b = blockIdx.z;
    const int m0 = blockIdx.x * 64, d0 = blockIdx.y * 64;
    const int t = threadIdx.x;

    if (t < 64) {
        const size_t grow = (size_t)b * 2048 + m0 + t;
        float s = 0.f;
#pragma unroll 8
        for (int i = 0; i < 32; ++i) s += part[grow * 32 + i];
        const float deg = mask[grow] ? (s + 1.0f) : 0.0f;
        const float dv = rsqrtf(fmaxf(deg, 1e-6f));
        dvl[grow] = dv;
        dsh[t] = mask[grow] ? dv * rnorm[grow] : 0.0f;
    }
    __syncthreads();

    const bf16* Xb = Xn + (size_t)b * 2048 * 256;
    const int rr = t >> 3;
    const int c8 = (t & 7) * 8;
#pragma unroll
    for (int i = 0; i < 2; ++i) {
        const int m = rr + i * 32;
        const int gm = m0 + m;
        const float s = dsh[m];
        const s8v v = *(const s8v*)&Xb[(size_t)gm * 256 + d0 + c8];
        ushort4 lo, hi;
        float f[8];
#pragma unroll
        for (int j = 0; j < 8; ++j) {
            f[j] = b2f((unsigned short)v[j]) * s;
            tile[m][c8 + j] = f[j];
        }
        lo.x = f2b(f[0]); lo.y = f2b(f[1]); lo.z = f2b(f[2]); lo.w = f2b(f[3]);
        hi.x = f2b(f[4]); hi.y = f2b(f[5]); hi.z = f2b(f[6]); hi.w = f2b(f[7]);
        bf16* yrow = Y + (size_t)b * 2048 * 256 + (size_t)gm * 256 + d0 + c8;
        *(ushort4*)yrow = lo;
        *(ushort4*)(yrow + 4) = hi;
    }
    __syncthreads();
    bf16* Yb = Yt + (size_t)b * 256 * 2048;
    const int dd = t >> 3;
    const int m8 = (t & 7) * 8;
#pragma unroll
    for (int i = 0; i < 2; ++i) {
        const int d = dd + i * 32;
        ushort4 lo, hi;
        lo.x = f2b(tile[m8 + 0][d]); lo.y = f2b(tile[m8 + 1][d]);
        lo.z = f2b(tile[m8 + 2][d]); lo.w = f2b(tile[m8 + 3][d]);
        hi.x = f2b(tile[m8 + 4][d]); hi.y = f2b(tile[m8 + 5][d]);
        hi.z = f2b(tile[m8 + 6][d]); hi.w = f2b(tile[m8 + 7][d]);
        bf16* yt = Yb + (size_t)(d0 + d) * 2048 + m0 + m8;
        *(ushort4*)yt = lo;
        *(ushort4*)(yt + 4) = hi;
    }
}

extern "C" void kernel_launch(void* const* d_in, const int* in_sizes, int n_in,
                              void* d_out, int out_size, void* d_ws, size_t ws_size,
                              hipStream_t stream)
{
    (void)in_sizes; (void)n_in; (void)out_size; (void)ws_size;
    const float* X  = (const float*)d_in[0];
    const int*  msk = (const int*)d_in[1];
    const float* W1 = (const float*)d_in[2];
    const float* b1 = (const float*)d_in[3];
    const float* W2 = (const float*)d_in[4];
    const float* b2 = (const float*)d_in[5];

    // scratch inside d_out (134,217,728 B), all dead before the final GEMM:
    char* O = (char*)d_out;
    bf16* S    = (bf16*)(O);                 // 67,108,864 B  [8][2048][2048]
    bf16* Xn   = (bf16*)(O + 67108864);      //  8,388,608 B  [8][2048][256]
    bf16* Yt   = (bf16*)(O + 75497472);      //  8,388,608 B  [8][256][2048]
    bf16* agg  = (bf16*)(O + 83886080);      //  8,388,608 B  [8][2048][256]
    bf16* Hf   = (bf16*)(O + 92274688);      //  8,388,608 B  [16384][256]
    float* dvl = (float*)(O + 100663296);    //     65,536 B  [8][2048]
    bf16* W1t  = (bf16*)(O + 100728832);     //    131,072 B
    bf16* W2t  = (bf16*)(O + 100859904);     //    131,072 B
    float* part= (float*)(O + 100990976);    //  2,097,152 B  [8][2048][32]
    bf16* Y    = (bf16*)(O + 103088128);     //  8,388,608 B  [8][2048][256]
    float* rnm = (float*)(O + 111476736);    //     65,536 B  [8][2048]
    bf16* P    = (bf16*)d_ws;                //  8,388,608 B  (survives final GEMM)

    xn_kernel<<<4352, 256, 0, stream>>>(X, Xn, rnm, W1, W2, W1t, W2t);

    // S = sigmoid(Xn Xn^T) bf16, + fused masked row-sum partials
    gemm_bt<128, 128, 0><<<2048, 256, 0, stream>>>(
        Xn, Xn, S, 2048, 2048, 256,
        (size_t)2048 * 256, (size_t)2048 * 256, (size_t)2048 * 2048,
        nullptr, nullptr, msk, nullptr, part, 16, 16);

    // fused fin_deg + Y/Yt build
    ytY_kernel<<<dim3(32, 4, 8), 256, 0, stream>>>(
        Xn, rnm, part, msk, dvl, Y, Yt);

    // agg = m_i ? d_i*(S@Y + Y_i) : 0, bf16  (128x64 tiles, XCD chunk = batch)
    gemm_bt<128, 64, 1><<<512, 256, 0, stream>>>(
        S, Yt, agg, 2048, 256, 2048,
        (size_t)2048 * 2048, (size_t)256 * 2048, (size_t)2048 * 256,
        Y, dvl, msk, nullptr, nullptr, 16, 4);

    // Hf = relu(agg @ W1 + b1)
    gemm_bt<64, 128, 2><<<512, 256, 0, stream>>>(
        agg, W1t, Hf, 16384, 256, 256, 0, 0, 0,
        nullptr, nullptr, nullptr, b1, nullptr, 256, 2);

    // P = Hf @ W2 + b2
    gemm_bt<64, 128, 3><<<512, 256, 0, stream>>>(
        Hf, W2t, P, 16384, 256, 256, 0, 0, 0,
        nullptr, nullptr, nullptr, b2, nullptr, 256, 2);

    // out = pairmask(sigmoid(P P^T)), f32, triangular + transposed emit
    gemm_tri<<<1088, 256, 0, stream>>>(P, (float*)d_out, msk);
}

// Round 8
// 119.025 us; speedup vs baseline: 1.2191x; 1.0971x over previous
//
#include <hip/hip_runtime.h>
#include <hip/hip_bf16.h>
#include <cstdint>

using bf16 = __hip_bfloat16;
typedef __attribute__((ext_vector_type(8))) short s8v;
typedef __attribute__((ext_vector_type(4))) float f32x4;

#define DEV static __device__ __forceinline__

DEV float b2f(unsigned short u) {
    union { float f; unsigned int i; } w; w.i = ((unsigned int)u) << 16; return w.f;
}
DEV unsigned short f2b(float x) {
    __hip_bfloat16 h = __float2bfloat16(x);
    return __builtin_bit_cast(unsigned short, h);
}
DEV float sigm(float x) { return 1.0f / (1.0f + __expf(-x)); }

DEV void gload16(const void* g, void* l) {
    __builtin_amdgcn_global_load_lds(
        (const __attribute__((address_space(1))) uint32_t*)g,
        (__attribute__((address_space(3))) uint32_t*)l, 16, 0, 0);
}

// ---------------------------------------------------------------------------
// bf16 GEMM, C = A (MxK row-major) * B^T (B NxK row-major). BMxBN tile,
// BK=64, 4 waves (2x2), 16x16x32 MFMA, 2-phase dbuf LDS (proven loop),
// XOR swizzle via inverse-swizzled global staging source. 1-D grid +
// bijective XCD chunk swizzle.
// Epilogues:
//  1: bf16 out = mask[row] ? d[row]*(acc + Yres[row,col]) : 0      (agg)
//  2: bf16 out = relu(acc + bias[col])
//  3: bf16 out = acc + bias[col]
// ---------------------------------------------------------------------------
template<int BM, int BN, int EPI>
__global__ __launch_bounds__(256)
void gemm_bt(const bf16* __restrict__ A, const bf16* __restrict__ B,
             void* __restrict__ C, const int M, const int N, const int K,
             const size_t sA, const size_t sB, const size_t sC,
             const bf16* __restrict__ Yres, const float* __restrict__ dval,
             const int* __restrict__ mask, const float* __restrict__ bias,
             const int GX, const int GY)
{
    constexpr int MR = BM / 32;
    constexpr int NR = BN / 32;
    constexpr int NA = BM / 32;
    constexpr int NB = BN / 32;
    constexpr int TILEB = (BM + BN) * 128;
    __shared__ char smb[2 * TILEB];

    const int nblk = gridDim.x;
    const int q = nblk >> 3;
    const int id = blockIdx.x;
    const int swz = (id & 7) * q + (id >> 3);
    const int gy = swz % GY;
    const int xz = swz / GY;
    const int gx = xz % GX;
    const int b = xz / GX;

    const char* Ab = (const char*)(A + (size_t)b * sA);
    const char* Bb = (const char*)(B + (size_t)b * sB);
    const int bm = gx * BM;
    const int bn = gy * BN;
    const int tid = threadIdx.x;
    const int lane = tid & 63;
    const int wv = tid >> 6;
    const int wr = wv >> 1, wc = wv & 1;
    const int fr = lane & 15, fq = lane >> 4;
    const size_t lda = (size_t)K * 2;

    constexpr int NMAX = (NA > NB) ? NA : NB;
    size_t aOff[NMAX], bOff[NMAX];
    int ldsO[NMAX];
#pragma unroll
    for (int i = 0; i < NMAX; ++i) {
        const int local = i * 4096 + wv * 1024;
        const int myOff = local + lane * 16;
        const int row = myOff >> 7;
        const int lc = (myOff & 127) ^ ((row & 7) << 4);
        ldsO[i] = local;
        aOff[i] = (size_t)(bm + row) * lda + lc;
        bOff[i] = (size_t)(bn + row) * lda + lc;
    }

    f32x4 acc[MR][NR];
#pragma unroll
    for (int m = 0; m < MR; ++m)
#pragma unroll
        for (int n = 0; n < NR; ++n)
            acc[m][n] = (f32x4){0.f, 0.f, 0.f, 0.f};

    auto STAGE = [&](int buf, size_t kb) {
        char* base = smb + buf * TILEB;
#pragma unroll
        for (int i = 0; i < NA; ++i)
            gload16(Ab + aOff[i] + kb, base + ldsO[i]);
#pragma unroll
        for (int i = 0; i < NB; ++i)
            gload16(Bb + bOff[i] + kb, base + BM * 128 + ldsO[i]);
    };

    auto COMPUTE = [&](int buf) {
        const char* sA_ = smb + buf * TILEB;
        const char* sB_ = sA_ + BM * 128;
#pragma unroll
        for (int kk = 0; kk < 2; ++kk) {
            s8v af[MR], bfv[NR];
#pragma unroll
            for (int m = 0; m < MR; ++m) {
                const int r = wr * (BM / 2) + m * 16 + fr;
                const int pb = (r << 7) | ((kk * 64 + fq * 16) ^ ((r & 7) << 4));
                af[m] = *(const s8v*)(sA_ + pb);
            }
#pragma unroll
            for (int n = 0; n < NR; ++n) {
                const int r = wc * (BN / 2) + n * 16 + fr;
                const int pb = (r << 7) | ((kk * 64 + fq * 16) ^ ((r & 7) << 4));
                bfv[n] = *(const s8v*)(sB_ + pb);
            }
#pragma unroll
            for (int m = 0; m < MR; ++m)
#pragma unroll
                for (int n = 0; n < NR; ++n)
                    acc[m][n] = __builtin_amdgcn_mfma_f32_16x16x32_bf16(
                        af[m], bfv[n], acc[m][n], 0, 0, 0);
        }
    };

    const int NT = K >> 6;
    STAGE(0, 0);
    asm volatile("s_waitcnt vmcnt(0)" ::: "memory");
    __syncthreads();
    int cur = 0;
    for (int t = 0; t < NT - 1; ++t) {
        STAGE(cur ^ 1, (size_t)(t + 1) * 128);
        COMPUTE(cur);
        asm volatile("s_waitcnt vmcnt(0)" ::: "memory");
        __syncthreads();
        cur ^= 1;
    }
    COMPUTE(cur);

    const int row0 = bm + wr * (BM / 2) + fq * 4;
    const int col0 = bn + wc * (BN / 2) + fr;
#pragma unroll
    for (int m = 0; m < MR; ++m) {
#pragma unroll
        for (int n = 0; n < NR; ++n) {
            const int col = col0 + n * 16;
#pragma unroll
            for (int r = 0; r < 4; ++r) {
                const int row = row0 + m * 16 + r;
                const float x = acc[m][n][r];
                const size_t cidx = (size_t)b * sC + (size_t)row * N + col;
                if constexpr (EPI == 1) {
                    const float dn = dval[(size_t)b * M + row];
                    const int mn = mask[(size_t)b * M + row];
                    const float yv =
                        b2f(__builtin_bit_cast(unsigned short,
                            Yres[(size_t)b * M * N + (size_t)row * N + col]));
                    ((bf16*)C)[cidx] = __float2bfloat16(mn ? dn * (x + yv) : 0.0f);
                } else if constexpr (EPI == 2) {
                    ((bf16*)C)[cidx] = __float2bfloat16(fmaxf(x + bias[col], 0.0f));
                } else {
                    ((bf16*)C)[cidx] = __float2bfloat16(x + bias[col]);
                }
            }
        }
    }
}

// ---------------------------------------------------------------------------
// Triangular S-GEMM: S[b] = sigmoid(Xn Xn^T) bf16 (symmetric), computed on
// the 136 upper-triangle 128x128 tiles per batch. Off-diagonal tiles also
// emit the transposed tile via a 32KB bf16 LDS buffer (byte-XOR swizzle).
// Fused masked degree partials: direct row-sums (col-masked, fr-reduced) ->
// part[row in xb-block][2*yb+wc]; off-diag col-sums (row-masked, fq-reduced)
// -> part[row in yb-block][2*xb+wr]. Slots {2c,2c+1:c>=r} U {2x,2x+1:x<r}
// cover 0..31 exactly once per row-block r. Grid 8*136, XCD chunk = batch.
// ---------------------------------------------------------------------------
__global__ __launch_bounds__(256)
void gemm_stri(const bf16* __restrict__ Xn, bf16* __restrict__ S,
               const int* __restrict__ mask, float* __restrict__ part)
{
    constexpr int K = 256, N = 2048;
    constexpr int TILEB = 256 * 128;       // 32 KB per buffer
    __shared__ char smb[2 * TILEB];

    const int id = blockIdx.x;
    const int swz = (id & 7) * 136 + (id >> 3);
    const int b = swz / 136;
    const int tri = swz - b * 136;
    int yb = (int)((sqrtf(8.0f * (float)tri + 1.0f) - 1.0f) * 0.5f);
    while ((yb + 1) * (yb + 2) / 2 <= tri) ++yb;
    while (yb * (yb + 1) / 2 > tri) --yb;
    const int xb = tri - yb * (yb + 1) / 2;   // xb <= yb
    const int bm = xb * 128, bn = yb * 128;

    const char* Ab = (const char*)(Xn + (size_t)b * N * K);
    const int tid = threadIdx.x;
    const int lane = tid & 63;
    const int wv = tid >> 6;
    const int wr = wv >> 1, wc = wv & 1;
    const int fr = lane & 15, fq = lane >> 4;
    const size_t lda = (size_t)K * 2;

    size_t aOff[4], bOff[4];
    int ldsO[4];
#pragma unroll
    for (int i = 0; i < 4; ++i) {
        const int local = i * 4096 + wv * 1024;
        const int myOff = local + lane * 16;
        const int row = myOff >> 7;
        const int lc = (myOff & 127) ^ ((row & 7) << 4);
        ldsO[i] = local;
        aOff[i] = (size_t)(bm + row) * lda + lc;
        bOff[i] = (size_t)(bn + row) * lda + lc;
    }

    f32x4 acc[4][4];
#pragma unroll
    for (int m = 0; m < 4; ++m)
#pragma unroll
        for (int n = 0; n < 4; ++n)
            acc[m][n] = (f32x4){0.f, 0.f, 0.f, 0.f};

    auto STAGE = [&](int buf, size_t kb) {
        char* base = smb + buf * TILEB;
#pragma unroll
        for (int i = 0; i < 4; ++i) {
            gload16(Ab + aOff[i] + kb, base + ldsO[i]);
            gload16(Ab + bOff[i] + kb, base + 16384 + ldsO[i]);
        }
    };

    auto COMPUTE = [&](int buf) {
        const char* sA_ = smb + buf * TILEB;
        const char* sB_ = sA_ + 16384;
#pragma unroll
        for (int kk = 0; kk < 2; ++kk) {
            s8v af[4], bfv[4];
#pragma unroll
            for (int m = 0; m < 4; ++m) {
                const int r = wr * 64 + m * 16 + fr;
                const int pb = (r << 7) | ((kk * 64 + fq * 16) ^ ((r & 7) << 4));
                af[m] = *(const s8v*)(sA_ + pb);
            }
#pragma unroll
            for (int n = 0; n < 4; ++n) {
                const int r = wc * 64 + n * 16 + fr;
                const int pb = (r << 7) | ((kk * 64 + fq * 16) ^ ((r & 7) << 4));
                bfv[n] = *(const s8v*)(sB_ + pb);
            }
#pragma unroll
            for (int m = 0; m < 4; ++m)
#pragma unroll
                for (int n = 0; n < 4; ++n)
                    acc[m][n] = __builtin_amdgcn_mfma_f32_16x16x32_bf16(
                        af[m], bfv[n], acc[m][n], 0, 0, 0);
        }
    };

    STAGE(0, 0);
    asm volatile("s_waitcnt vmcnt(0)" ::: "memory");
    __syncthreads();
    int cur = 0;
    for (int t = 0; t < 3; ++t) {
        STAGE(cur ^ 1, (size_t)(t + 1) * 128);
        COMPUTE(cur);
        asm volatile("s_waitcnt vmcnt(0)" ::: "memory");
        __syncthreads();
        cur ^= 1;
    }
    COMPUTE(cur);   // reads buf1; buf0 free (last read before t=2 barrier)

    const int row0L = wr * 64 + fq * 4;    // local row base
    const int col0L = wc * 64 + fr;        // local col base
    const bool diag = (xb == yb);
    bf16* Sb = S + (size_t)b * (size_t)N * N;
    char* smT = smb;                       // 32 KB bf16 transpose tile (buf0)

    int cmv[4];
#pragma unroll
    for (int n = 0; n < 4; ++n)
        cmv[n] = mask[(size_t)b * N + bn + col0L + n * 16];
    float cs[4] = {0.f, 0.f, 0.f, 0.f};

#pragma unroll
    for (int m = 0; m < 4; ++m) {
        int rmv[4];
#pragma unroll
        for (int r = 0; r < 4; ++r)
            rmv[r] = mask[(size_t)b * N + bm + row0L + m * 16 + r];
        float rs[4] = {0.f, 0.f, 0.f, 0.f};
#pragma unroll
        for (int n = 0; n < 4; ++n) {
            const int colL = col0L + n * 16;
            ushort4 u4;
#pragma unroll
            for (int r = 0; r < 4; ++r) {
                const float x = sigm(acc[m][n][r]);
                Sb[(size_t)(bm + row0L + m * 16 + r) * N + bn + colL] =
                    __float2bfloat16(x);
                if (cmv[n]) rs[r] += x;
                if (rmv[r]) cs[n] += x;
                ((unsigned short*)&u4)[r] = f2b(x);
            }
            if (!diag) {
                const int rowb = (row0L + m * 16) * 2;
                *(ushort4*)(smT + colL * 256 + (rowb ^ ((colL & 15) << 4))) = u4;
            }
        }
#pragma unroll
        for (int off = 1; off < 16; off <<= 1)
#pragma unroll
            for (int r = 0; r < 4; ++r) rs[r] += __shfl_xor(rs[r], off);
        if (fr == 0) {
#pragma unroll
            for (int r = 0; r < 4; ++r)
                part[((size_t)b * N + bm + row0L + m * 16 + r) * 32 +
                     yb * 2 + wc] = rs[r];
        }
    }

    if (!diag) {
        // col-sums -> degree partials for the transposed tile's rows
#pragma unroll
        for (int n = 0; n < 4; ++n) {
            cs[n] += __shfl_xor(cs[n], 16);
            cs[n] += __shfl_xor(cs[n], 32);
        }
        if (fq == 0) {
#pragma unroll
            for (int n = 0; n < 4; ++n)
                part[((size_t)b * N + bn + wc * 64 + n * 16 + fr) * 32 +
                     xb * 2 + wr] = cs[n];
        }
        __syncthreads();
        // write transposed tile: rows bn-panel, cols bm-panel
#pragma unroll
        for (int it = 0; it < 8; ++it) {
            const int cL = it * 16 + (tid >> 4);
            const int q8 = tid & 15;
            const s8v v = *(const s8v*)(smT + cL * 256 +
                                        ((q8 * 16) ^ ((cL & 15) << 4)));
            *(s8v*)&Sb[(size_t)(bn + cL) * N + bm + q8 * 8] = v;
        }
    }
}

// ---------------------------------------------------------------------------
// Final symmetric GEMM: out[b] = pairmask(sigmoid(P P^T)), f32, upper
// triangle of 128x128 tiles; off-diag emits transpose via LDS (R7-proven).
// ---------------------------------------------------------------------------
__global__ __launch_bounds__(256)
void gemm_tri(const bf16* __restrict__ Pm, float* __restrict__ C,
              const int* __restrict__ mask)
{
    constexpr int K = 256, N = 2048;
    constexpr int TILEB = 256 * 128;
    __shared__ char smb[2 * TILEB];

    const int id = blockIdx.x;
    const int swz = (id & 7) * 136 + (id >> 3);
    const int b = swz / 136;
    const int tri = swz - b * 136;
    int yb = (int)((sqrtf(8.0f * (float)tri + 1.0f) - 1.0f) * 0.5f);
    while ((yb + 1) * (yb + 2) / 2 <= tri) ++yb;
    while (yb * (yb + 1) / 2 > tri) --yb;
    const int xb = tri - yb * (yb + 1) / 2;
    const int bm = xb * 128, bn = yb * 128;

    const char* Ab = (const char*)(Pm + (size_t)b * N * K);
    const int tid = threadIdx.x;
    const int lane = tid & 63;
    const int wv = tid >> 6;
    const int wr = wv >> 1, wc = wv & 1;
    const int fr = lane & 15, fq = lane >> 4;
    const size_t lda = (size_t)K * 2;

    size_t aOff[4], bOff[4];
    int ldsO[4];
#pragma unroll
    for (int i = 0; i < 4; ++i) {
        const int local = i * 4096 + wv * 1024;
        const int myOff = local + lane * 16;
        const int row = myOff >> 7;
        const int lc = (myOff & 127) ^ ((row & 7) << 4);
        ldsO[i] = local;
        aOff[i] = (size_t)(bm + row) * lda + lc;
        bOff[i] = (size_t)(bn + row) * lda + lc;
    }

    f32x4 acc[4][4];
#pragma unroll
    for (int m = 0; m < 4; ++m)
#pragma unroll
        for (int n = 0; n < 4; ++n)
            acc[m][n] = (f32x4){0.f, 0.f, 0.f, 0.f};

    auto STAGE = [&](int buf, size_t kb) {
        char* base = smb + buf * TILEB;
#pragma unroll
        for (int i = 0; i < 4; ++i) {
            gload16(Ab + aOff[i] + kb, base + ldsO[i]);
            gload16(Ab + bOff[i] + kb, base + 16384 + ldsO[i]);
        }
    };

    auto COMPUTE = [&](int buf) {
        const char* sA_ = smb + buf * TILEB;
        const char* sB_ = sA_ + 16384;
#pragma unroll
        for (int kk = 0; kk < 2; ++kk) {
            s8v af[4], bfv[4];
#pragma unroll
            for (int m = 0; m < 4; ++m) {
                const int r = wr * 64 + m * 16 + fr;
                const int pb = (r << 7) | ((kk * 64 + fq * 16) ^ ((r & 7) << 4));
                af[m] = *(const s8v*)(sA_ + pb);
            }
#pragma unroll
            for (int n = 0; n < 4; ++n) {
                const int r = wc * 64 + n * 16 + fr;
                const int pb = (r << 7) | ((kk * 64 + fq * 16) ^ ((r & 7) << 4));
                bfv[n] = *(const s8v*)(sB_ + pb);
            }
#pragma unroll
            for (int m = 0; m < 4; ++m)
#pragma unroll
                for (int n = 0; n < 4; ++n)
                    acc[m][n] = __builtin_amdgcn_mfma_f32_16x16x32_bf16(
                        af[m], bfv[n], acc[m][n], 0, 0, 0);
        }
    };

    STAGE(0, 0);
    asm volatile("s_waitcnt vmcnt(0)" ::: "memory");
    __syncthreads();
    int cur = 0;
    for (int t = 0; t < 3; ++t) {
        STAGE(cur ^ 1, (size_t)(t + 1) * 128);
        COMPUTE(cur);
        asm volatile("s_waitcnt vmcnt(0)" ::: "memory");
        __syncthreads();
        cur ^= 1;
    }
    COMPUTE(cur);
    __syncthreads();

    const int row0L = wr * 64 + fq * 4;
    const int col0L = wc * 64 + fr;
    const bool diag = (xb == yb);
    float4* ft = (float4*)smb;

    int cmv[4];
#pragma unroll
    for (int n = 0; n < 4; ++n)
        cmv[n] = mask[(size_t)b * N + bn + col0L + n * 16];
#pragma unroll
    for (int m = 0; m < 4; ++m) {
        int rmv[4];
#pragma unroll
        for (int r = 0; r < 4; ++r)
            rmv[r] = mask[(size_t)b * N + bm + row0L + m * 16 + r];
#pragma unroll
        for (int n = 0; n < 4; ++n) {
            float vv[4];
#pragma unroll
            for (int r = 0; r < 4; ++r)
                vv[r] = (rmv[r] & cmv[n]) ? sigm(acc[m][n][r]) : 0.0f;
#pragma unroll
            for (int r = 0; r < 4; ++r)
                C[(size_t)b * N * N +
                  (size_t)(bm + row0L + m * 16 + r) * N + bn + col0L + n * 16] = vv[r];
            const int colL = col0L + n * 16;
            const int qd = (row0L + m * 16) >> 2;
            ft[colL * 32 + (qd ^ (colL & 31))] =
                make_float4(vv[0], vv[1], vv[2], vv[3]);
        }
    }
    if (!diag) {
        __syncthreads();
#pragma unroll 4
        for (int it = 0; it < 16; ++it) {
            const int cL = it * 8 + (tid >> 5);
            const int qd = tid & 31;
            const float4 v4 = ft[cL * 32 + (qd ^ (cL & 31))];
            *(float4*)&C[(size_t)b * N * N +
                         (size_t)(bn + cL) * N + bm + qd * 4] = v4;
        }
    }
}

// ---------------------------------------------------------------------------
// blocks [0,4096): row-normalize X -> Xn (bf16) + rnorm. One wave per row.
// blocks [4096,4352): transpose W1,W2 to bf16.
// ---------------------------------------------------------------------------
__global__ __launch_bounds__(256)
void xn_kernel(const float* __restrict__ X, bf16* __restrict__ Xn,
               float* __restrict__ rnorm,
               const float* __restrict__ W1, const float* __restrict__ W2,
               bf16* __restrict__ W1t, bf16* __restrict__ W2t)
{
    if (blockIdx.x >= 4096) {
        const int idx = (blockIdx.x - 4096) * 256 + threadIdx.x;
        const int h = idx & 255, d = idx >> 8;
        W1t[h * 256 + d] = __float2bfloat16(W1[idx]);
        W2t[h * 256 + d] = __float2bfloat16(W2[idx]);
        return;
    }
    const int lane = threadIdx.x & 63;
    const size_t row = (size_t)blockIdx.x * 4 + (threadIdx.x >> 6);
    const float4 v = *(const float4*)&X[row * 256 + lane * 4];
    float ss = v.x * v.x + v.y * v.y + v.z * v.z + v.w * v.w;
#pragma unroll
    for (int o = 32; o; o >>= 1) ss += __shfl_xor(ss, o);
    const float nrm = fmaxf(sqrtf(ss), 1e-12f);
    const float inv = 1.0f / nrm;
    ushort4 o4;
    o4.x = f2b(v.x * inv); o4.y = f2b(v.y * inv);
    o4.z = f2b(v.z * inv); o4.w = f2b(v.w * inv);
    *(ushort4*)&Xn[row * 256 + lane * 4] = o4;
    if (lane == 0) rnorm[row] = nrm;
}

// ---------------------------------------------------------------------------
// Fused degree-finalize + Y/Yt build. Per block: 64 rows x 64 cols of Xn.
// ---------------------------------------------------------------------------
__global__ __launch_bounds__(256)
void ytY_kernel(const bf16* __restrict__ Xn, const float* __restrict__ rnorm,
                const float* __restrict__ part, const int* __restrict__ mask,
                float* __restrict__ dvl, bf16* __restrict__ Y,
                bf16* __restrict__ Yt)
{
    __shared__ float tile[64][65];
    __shared__ float dsh[64];
    const int b = blockIdx.z;
    const int m0 = blockIdx.x * 64, d0 = blockIdx.y * 64;
    const int t = threadIdx.x;

    if (t < 64) {
        const size_t grow = (size_t)b * 2048 + m0 + t;
        float s = 0.f;
#pragma unroll 8
        for (int i = 0; i < 32; ++i) s += part[grow * 32 + i];
        const float deg = mask[grow] ? (s + 1.0f) : 0.0f;
        const float dv = rsqrtf(fmaxf(deg, 1e-6f));
        dvl[grow] = dv;
        dsh[t] = mask[grow] ? dv * rnorm[grow] : 0.0f;
    }
    __syncthreads();

    const bf16* Xb = Xn + (size_t)b * 2048 * 256;
    const int rr = t >> 3;
    const int c8 = (t & 7) * 8;
#pragma unroll
    for (int i = 0; i < 2; ++i) {
        const int m = rr + i * 32;
        const int gm = m0 + m;
        const float s = dsh[m];
        const s8v v = *(const s8v*)&Xb[(size_t)gm * 256 + d0 + c8];
        ushort4 lo, hi;
        float f[8];
#pragma unroll
        for (int j = 0; j < 8; ++j) {
            f[j] = b2f((unsigned short)v[j]) * s;
            tile[m][c8 + j] = f[j];
        }
        lo.x = f2b(f[0]); lo.y = f2b(f[1]); lo.z = f2b(f[2]); lo.w = f2b(f[3]);
        hi.x = f2b(f[4]); hi.y = f2b(f[5]); hi.z = f2b(f[6]); hi.w = f2b(f[7]);
        bf16* yrow = Y + (size_t)b * 2048 * 256 + (size_t)gm * 256 + d0 + c8;
        *(ushort4*)yrow = lo;
        *(ushort4*)(yrow + 4) = hi;
    }
    __syncthreads();
    bf16* Yb = Yt + (size_t)b * 256 * 2048;
    const int dd = t >> 3;
    const int m8 = (t & 7) * 8;
#pragma unroll
    for (int i = 0; i < 2; ++i) {
        const int d = dd + i * 32;
        ushort4 lo, hi;
        lo.x = f2b(tile[m8 + 0][d]); lo.y = f2b(tile[m8 + 1][d]);
        lo.z = f2b(tile[m8 + 2][d]); lo.w = f2b(tile[m8 + 3][d]);
        hi.x = f2b(tile[m8 + 4][d]); hi.y = f2b(tile[m8 + 5][d]);
        hi.z = f2b(tile[m8 + 6][d]); hi.w = f2b(tile[m8 + 7][d]);
        bf16* yt = Yb + (size_t)(d0 + d) * 2048 + m0 + m8;
        *(ushort4*)yt = lo;
        *(ushort4*)(yt + 4) = hi;
    }
}

extern "C" void kernel_launch(void* const* d_in, const int* in_sizes, int n_in,
                              void* d_out, int out_size, void* d_ws, size_t ws_size,
                              hipStream_t stream)
{
    (void)in_sizes; (void)n_in; (void)out_size; (void)ws_size;
    const float* X  = (const float*)d_in[0];
    const int*  msk = (const int*)d_in[1];
    const float* W1 = (const float*)d_in[2];
    const float* b1 = (const float*)d_in[3];
    const float* W2 = (const float*)d_in[4];
    const float* b2 = (const float*)d_in[5];

    // scratch inside d_out (134,217,728 B), all dead before the final GEMM:
    char* O = (char*)d_out;
    bf16* S    = (bf16*)(O);                 // 67,108,864 B  [8][2048][2048]
    bf16* Xn   = (bf16*)(O + 67108864);      //  8,388,608 B  [8][2048][256]
    bf16* Yt   = (bf16*)(O + 75497472);      //  8,388,608 B  [8][256][2048]
    bf16* agg  = (bf16*)(O + 83886080);      //  8,388,608 B  [8][2048][256]
    bf16* Hf   = (bf16*)(O + 92274688);      //  8,388,608 B  [16384][256]
    float* dvl = (float*)(O + 100663296);    //     65,536 B  [8][2048]
    bf16* W1t  = (bf16*)(O + 100728832);     //    131,072 B
    bf16* W2t  = (bf16*)(O + 100859904);     //    131,072 B
    float* part= (float*)(O + 100990976);    //  2,097,152 B  [8][2048][32]
    bf16* Y    = (bf16*)(O + 103088128);     //  8,388,608 B  [8][2048][256]
    float* rnm = (float*)(O + 111476736);    //     65,536 B  [8][2048]
    bf16* P    = (bf16*)d_ws;                //  8,388,608 B  (survives final GEMM)

    xn_kernel<<<4352, 256, 0, stream>>>(X, Xn, rnm, W1, W2, W1t, W2t);

    // S = sigmoid(Xn Xn^T) bf16, triangular + transpose emit + degree partials
    gemm_stri<<<1088, 256, 0, stream>>>(Xn, S, msk, part);

    // fused fin_deg + Y/Yt build
    ytY_kernel<<<dim3(32, 4, 8), 256, 0, stream>>>(
        Xn, rnm, part, msk, dvl, Y, Yt);

    // agg = m_i ? d_i*(S@Y + Y_i) : 0, bf16  (128x64 tiles, XCD chunk = batch)
    gemm_bt<128, 64, 1><<<512, 256, 0, stream>>>(
        S, Yt, agg, 2048, 256, 2048,
        (size_t)2048 * 2048, (size_t)256 * 2048, (size_t)2048 * 256,
        Y, dvl, msk, nullptr, 16, 4);

    // Hf = relu(agg @ W1 + b1)
    gemm_bt<64, 128, 2><<<512, 256, 0, stream>>>(
        agg, W1t, Hf, 16384, 256, 256, 0, 0, 0,
        nullptr, nullptr, nullptr, b1, 256, 2);

    // P = Hf @ W2 + b2
    gemm_bt<64, 128, 3><<<512, 256, 0, stream>>>(
        Hf, W2t, P, 16384, 256, 256, 0, 0, 0,
        nullptr, nullptr, nullptr, b2, 256, 2);

    // out = pairmask(sigmoid(P P^T)), f32, triangular + transposed emit
    gemm_tri<<<1088, 256, 0, stream>>>(P, (float*)d_out, msk);
}

// Round 9
// 116.445 us; speedup vs baseline: 1.2461x; 1.0222x over previous
//
#include <hip/hip_runtime.h>
#include <hip/hip_bf16.h>
#include <cstdint>

using bf16 = __hip_bfloat16;
typedef __attribute__((ext_vector_type(8))) short s8v;
typedef __attribute__((ext_vector_type(4))) float f32x4;

#define DEV static __device__ __forceinline__

DEV float b2f(unsigned short u) {
    union { float f; unsigned int i; } w; w.i = ((unsigned int)u) << 16; return w.f;
}
DEV unsigned short f2b(float x) {
    __hip_bfloat16 h = __float2bfloat16(x);
    return __builtin_bit_cast(unsigned short, h);
}
DEV float sigm(float x) { return 1.0f / (1.0f + __expf(-x)); }

DEV void gload16(const void* g, void* l) {
    __builtin_amdgcn_global_load_lds(
        (const __attribute__((address_space(1))) uint32_t*)g,
        (__attribute__((address_space(3))) uint32_t*)l, 16, 0, 0);
}

// ---------------------------------------------------------------------------
// bf16 GEMM, C = A (MxK row-major) * B^T (B NxK row-major). BMxBN tile,
// BK=64, 4 waves (2x2), 16x16x32 MFMA, 2-phase dbuf LDS (proven loop),
// XOR swizzle via inverse-swizzled global staging source. 1-D grid +
// bijective XCD chunk swizzle. Used for agg only now (EPI=1):
//  1: bf16 out = mask[row] ? d[row]*(acc + Yres[row,col]) : 0
// ---------------------------------------------------------------------------
template<int BM, int BN, int EPI>
__global__ __launch_bounds__(256)
void gemm_bt(const bf16* __restrict__ A, const bf16* __restrict__ B,
             void* __restrict__ C, const int M, const int N, const int K,
             const size_t sA, const size_t sB, const size_t sC,
             const bf16* __restrict__ Yres, const float* __restrict__ dval,
             const int* __restrict__ mask, const int GX, const int GY)
{
    constexpr int MR = BM / 32;
    constexpr int NR = BN / 32;
    constexpr int NA = BM / 32;
    constexpr int NB = BN / 32;
    constexpr int TILEB = (BM + BN) * 128;
    __shared__ char smb[2 * TILEB];

    const int nblk = gridDim.x;
    const int q = nblk >> 3;
    const int id = blockIdx.x;
    const int swz = (id & 7) * q + (id >> 3);
    const int gy = swz % GY;
    const int xz = swz / GY;
    const int gx = xz % GX;
    const int b = xz / GX;

    const char* Ab = (const char*)(A + (size_t)b * sA);
    const char* Bb = (const char*)(B + (size_t)b * sB);
    const int bm = gx * BM;
    const int bn = gy * BN;
    const int tid = threadIdx.x;
    const int lane = tid & 63;
    const int wv = tid >> 6;
    const int wr = wv >> 1, wc = wv & 1;
    const int fr = lane & 15, fq = lane >> 4;
    const size_t lda = (size_t)K * 2;

    constexpr int NMAX = (NA > NB) ? NA : NB;
    size_t aOff[NMAX], bOff[NMAX];
    int ldsO[NMAX];
#pragma unroll
    for (int i = 0; i < NMAX; ++i) {
        const int local = i * 4096 + wv * 1024;
        const int myOff = local + lane * 16;
        const int row = myOff >> 7;
        const int lc = (myOff & 127) ^ ((row & 7) << 4);
        ldsO[i] = local;
        aOff[i] = (size_t)(bm + row) * lda + lc;
        bOff[i] = (size_t)(bn + row) * lda + lc;
    }

    f32x4 acc[MR][NR];
#pragma unroll
    for (int m = 0; m < MR; ++m)
#pragma unroll
        for (int n = 0; n < NR; ++n)
            acc[m][n] = (f32x4){0.f, 0.f, 0.f, 0.f};

    auto STAGE = [&](int buf, size_t kb) {
        char* base = smb + buf * TILEB;
#pragma unroll
        for (int i = 0; i < NA; ++i)
            gload16(Ab + aOff[i] + kb, base + ldsO[i]);
#pragma unroll
        for (int i = 0; i < NB; ++i)
            gload16(Bb + bOff[i] + kb, base + BM * 128 + ldsO[i]);
    };

    auto COMPUTE = [&](int buf) {
        const char* sA_ = smb + buf * TILEB;
        const char* sB_ = sA_ + BM * 128;
#pragma unroll
        for (int kk = 0; kk < 2; ++kk) {
            s8v af[MR], bfv[NR];
#pragma unroll
            for (int m = 0; m < MR; ++m) {
                const int r = wr * (BM / 2) + m * 16 + fr;
                const int pb = (r << 7) | ((kk * 64 + fq * 16) ^ ((r & 7) << 4));
                af[m] = *(const s8v*)(sA_ + pb);
            }
#pragma unroll
            for (int n = 0; n < NR; ++n) {
                const int r = wc * (BN / 2) + n * 16 + fr;
                const int pb = (r << 7) | ((kk * 64 + fq * 16) ^ ((r & 7) << 4));
                bfv[n] = *(const s8v*)(sB_ + pb);
            }
#pragma unroll
            for (int m = 0; m < MR; ++m)
#pragma unroll
                for (int n = 0; n < NR; ++n)
                    acc[m][n] = __builtin_amdgcn_mfma_f32_16x16x32_bf16(
                        af[m], bfv[n], acc[m][n], 0, 0, 0);
        }
    };

    const int NT = K >> 6;
    STAGE(0, 0);
    asm volatile("s_waitcnt vmcnt(0)" ::: "memory");
    __syncthreads();
    int cur = 0;
    for (int t = 0; t < NT - 1; ++t) {
        STAGE(cur ^ 1, (size_t)(t + 1) * 128);
        COMPUTE(cur);
        asm volatile("s_waitcnt vmcnt(0)" ::: "memory");
        __syncthreads();
        cur ^= 1;
    }
    COMPUTE(cur);

    const int row0 = bm + wr * (BM / 2) + fq * 4;
    const int col0 = bn + wc * (BN / 2) + fr;
#pragma unroll
    for (int m = 0; m < MR; ++m) {
#pragma unroll
        for (int n = 0; n < NR; ++n) {
            const int col = col0 + n * 16;
#pragma unroll
            for (int r = 0; r < 4; ++r) {
                const int row = row0 + m * 16 + r;
                const float x = acc[m][n][r];
                const size_t cidx = (size_t)b * sC + (size_t)row * N + col;
                const float dn = dval[(size_t)b * M + row];
                const int mn = mask[(size_t)b * M + row];
                const float yv =
                    b2f(__builtin_bit_cast(unsigned short,
                        Yres[(size_t)b * M * N + (size_t)row * N + col]));
                ((bf16*)C)[cidx] = __float2bfloat16(mn ? dn * (x + yv) : 0.0f);
            }
        }
    }
}

// ---------------------------------------------------------------------------
// Fused MLP: P = (relu(agg @ W1 + b1)) @ W2 + b2, bf16. One block = 64 rows,
// 8 waves (2x4), wave-tile 32x64, BK=64, NT=4 per stage. Stage-1 output is
// written (relu+b1, bf16) to a 32KB LDS Hf buffer laid out as 4 K-chunks of
// [64][64 bf16] with the standard XOR swizzle; stage-2 reads A-frags from it.
// LDS = 2x8K (A bufs) + 2x32K (B bufs) + 32K (Hf) = 112 KB.
// ---------------------------------------------------------------------------
__global__ __launch_bounds__(512)
void mlp_fused(const bf16* __restrict__ Ag, const bf16* __restrict__ W1t,
               const float* __restrict__ b1, const bf16* __restrict__ W2t,
               const float* __restrict__ b2, bf16* __restrict__ P)
{
    __shared__ char smb[114688];
    char* Ab2 = smb;             // 2 x 8192
    char* Bb2 = smb + 16384;     // 2 x 32768
    char* Hl  = smb + 81920;     // 32768 = 4 chunks x 8192

    const int tid = threadIdx.x, lane = tid & 63, wv = tid >> 6;
    const int wr = wv >> 2, wc = wv & 3;
    const int fr = lane & 15, fq = lane >> 4;
    const int bm = blockIdx.x * 64;
    const char* Agb = (const char*)Ag;
    const char* W1b = (const char*)W1t;
    const char* W2b = (const char*)W2t;

    // A staging: 8KB tile [64][64bf16], 1 instr/thread
    const int ldsA = wv * 1024;
    const int myA = ldsA + lane * 16;
    const int rA = myA >> 7;
    const size_t aOff = (size_t)(bm + rA) * 512 +
                        ((myA & 127) ^ ((rA & 7) << 4));

    // B staging: 32KB tile [256][64bf16], 4 instr/thread
    size_t bOff[4];
    int ldsB[4];
#pragma unroll
    for (int i = 0; i < 4; ++i) {
        const int local = i * 8192 + wv * 1024;
        const int my = local + lane * 16;
        const int r = my >> 7;
        ldsB[i] = local;
        bOff[i] = (size_t)r * 512 + ((my & 127) ^ ((r & 7) << 4));
    }

    auto STAGE1 = [&](int buf, int t) {
        const size_t kb = (size_t)t * 128;
        gload16(Agb + aOff + kb, Ab2 + buf * 8192 + ldsA);
#pragma unroll
        for (int i = 0; i < 4; ++i)
            gload16(W1b + bOff[i] + kb, Bb2 + buf * 32768 + ldsB[i]);
    };
    auto STAGE2 = [&](int buf, int t) {
        const size_t kb = (size_t)t * 128;
#pragma unroll
        for (int i = 0; i < 4; ++i)
            gload16(W2b + bOff[i] + kb, Bb2 + buf * 32768 + ldsB[i]);
    };

    f32x4 acc[2][4];
#pragma unroll
    for (int m = 0; m < 2; ++m)
#pragma unroll
        for (int n = 0; n < 4; ++n)
            acc[m][n] = (f32x4){0.f, 0.f, 0.f, 0.f};

    auto CMP1 = [&](int buf) {
#pragma unroll
        for (int kk = 0; kk < 2; ++kk) {
            s8v af[2], bv[4];
#pragma unroll
            for (int m = 0; m < 2; ++m) {
                const int r = wr * 32 + m * 16 + fr;
                const int pb = (r << 7) | ((kk * 64 + fq * 16) ^ ((r & 7) << 4));
                af[m] = *(const s8v*)(Ab2 + buf * 8192 + pb);
            }
#pragma unroll
            for (int n = 0; n < 4; ++n) {
                const int r = wc * 64 + n * 16 + fr;
                const int pb = (r << 7) | ((kk * 64 + fq * 16) ^ ((r & 7) << 4));
                bv[n] = *(const s8v*)(Bb2 + buf * 32768 + pb);
            }
#pragma unroll
            for (int m = 0; m < 2; ++m)
#pragma unroll
                for (int n = 0; n < 4; ++n)
                    acc[m][n] = __builtin_amdgcn_mfma_f32_16x16x32_bf16(
                        af[m], bv[n], acc[m][n], 0, 0, 0);
        }
    };
    auto CMP2 = [&](int buf, int t) {
#pragma unroll
        for (int kk = 0; kk < 2; ++kk) {
            s8v af[2], bv[4];
#pragma unroll
            for (int m = 0; m < 2; ++m) {
                const int r = wr * 32 + m * 16 + fr;
                const int pb = (r << 7) | ((kk * 64 + fq * 16) ^ ((r & 7) << 4));
                af[m] = *(const s8v*)(Hl + t * 8192 + pb);
            }
#pragma unroll
            for (int n = 0; n < 4; ++n) {
                const int r = wc * 64 + n * 16 + fr;
                const int pb = (r << 7) | ((kk * 64 + fq * 16) ^ ((r & 7) << 4));
                bv[n] = *(const s8v*)(Bb2 + buf * 32768 + pb);
            }
#pragma unroll
            for (int m = 0; m < 2; ++m)
#pragma unroll
                for (int n = 0; n < 4; ++n)
                    acc[m][n] = __builtin_amdgcn_mfma_f32_16x16x32_bf16(
                        af[m], bv[n], acc[m][n], 0, 0, 0);
        }
    };

    // ---- stage 1: Hf = relu(agg @ W1 + b1) -> LDS ----
    STAGE1(0, 0);
    asm volatile("s_waitcnt vmcnt(0)" ::: "memory");
    __syncthreads();
    int cur = 0;
    for (int t = 0; t < 3; ++t) {
        STAGE1(cur ^ 1, t + 1);
        CMP1(cur);
        asm volatile("s_waitcnt vmcnt(0)" ::: "memory");
        __syncthreads();
        cur ^= 1;
    }
    CMP1(cur);

    float bv1[4];
#pragma unroll
    for (int n = 0; n < 4; ++n) bv1[n] = b1[wc * 64 + n * 16 + fr];
    const int r0 = wr * 32 + fq * 4;
#pragma unroll
    for (int m = 0; m < 2; ++m) {
#pragma unroll
        for (int n = 0; n < 4; ++n) {
            const int colw = n * 16 + fr;      // 0..63 within chunk wc
#pragma unroll
            for (int r = 0; r < 4; ++r) {
                const int row = r0 + m * 16 + r;
                const float x = fmaxf(acc[m][n][r] + bv1[n], 0.0f);
                *(unsigned short*)(Hl + wc * 8192 + (row << 7) +
                                   ((colw * 2) ^ ((row & 7) << 4))) = f2b(x);
            }
            acc[m][n] = (f32x4){0.f, 0.f, 0.f, 0.f};
        }
    }
    __syncthreads();   // Hf visible; B bufs free (last read done by all waves)

    // ---- stage 2: P = Hf @ W2 + b2 ----
    STAGE2(0, 0);
    asm volatile("s_waitcnt vmcnt(0)" ::: "memory");
    __syncthreads();
    cur = 0;
    for (int t = 0; t < 3; ++t) {
        STAGE2(cur ^ 1, t + 1);
        CMP2(cur, t);
        asm volatile("s_waitcnt vmcnt(0)" ::: "memory");
        __syncthreads();
        cur ^= 1;
    }
    CMP2(cur, 3);

    float bv2[4];
#pragma unroll
    for (int n = 0; n < 4; ++n) bv2[n] = b2[wc * 64 + n * 16 + fr];
#pragma unroll
    for (int m = 0; m < 2; ++m)
#pragma unroll
        for (int n = 0; n < 4; ++n)
#pragma unroll
            for (int r = 0; r < 4; ++r)
                P[(size_t)(bm + r0 + m * 16 + r) * 256 + wc * 64 + n * 16 + fr] =
                    __float2bfloat16(acc[m][n][r] + bv2[n]);
}

// ---------------------------------------------------------------------------
// Triangular S-GEMM: S[b] = sigmoid(Xn Xn^T) bf16 (symmetric), 136 upper-
// triangle 128x128 tiles/batch, transpose emit via LDS, fused degree
// partials (row-sums direct; col-sums for the mirrored tile). (R8-proven)
// ---------------------------------------------------------------------------
__global__ __launch_bounds__(256)
void gemm_stri(const bf16* __restrict__ Xn, bf16* __restrict__ S,
               const int* __restrict__ mask, float* __restrict__ part)
{
    constexpr int K = 256, N = 2048;
    constexpr int TILEB = 256 * 128;
    __shared__ char smb[2 * TILEB];

    const int id = blockIdx.x;
    const int swz = (id & 7) * 136 + (id >> 3);
    const int b = swz / 136;
    const int tri = swz - b * 136;
    int yb = (int)((sqrtf(8.0f * (float)tri + 1.0f) - 1.0f) * 0.5f);
    while ((yb + 1) * (yb + 2) / 2 <= tri) ++yb;
    while (yb * (yb + 1) / 2 > tri) --yb;
    const int xb = tri - yb * (yb + 1) / 2;
    const int bm = xb * 128, bn = yb * 128;

    const char* Ab = (const char*)(Xn + (size_t)b * N * K);
    const int tid = threadIdx.x;
    const int lane = tid & 63;
    const int wv = tid >> 6;
    const int wr = wv >> 1, wc = wv & 1;
    const int fr = lane & 15, fq = lane >> 4;
    const size_t lda = (size_t)K * 2;

    size_t aOff[4], bOff[4];
    int ldsO[4];
#pragma unroll
    for (int i = 0; i < 4; ++i) {
        const int local = i * 4096 + wv * 1024;
        const int myOff = local + lane * 16;
        const int row = myOff >> 7;
        const int lc = (myOff & 127) ^ ((row & 7) << 4);
        ldsO[i] = local;
        aOff[i] = (size_t)(bm + row) * lda + lc;
        bOff[i] = (size_t)(bn + row) * lda + lc;
    }

    f32x4 acc[4][4];
#pragma unroll
    for (int m = 0; m < 4; ++m)
#pragma unroll
        for (int n = 0; n < 4; ++n)
            acc[m][n] = (f32x4){0.f, 0.f, 0.f, 0.f};

    auto STAGE = [&](int buf, size_t kb) {
        char* base = smb + buf * TILEB;
#pragma unroll
        for (int i = 0; i < 4; ++i) {
            gload16(Ab + aOff[i] + kb, base + ldsO[i]);
            gload16(Ab + bOff[i] + kb, base + 16384 + ldsO[i]);
        }
    };

    auto COMPUTE = [&](int buf) {
        const char* sA_ = smb + buf * TILEB;
        const char* sB_ = sA_ + 16384;
#pragma unroll
        for (int kk = 0; kk < 2; ++kk) {
            s8v af[4], bfv[4];
#pragma unroll
            for (int m = 0; m < 4; ++m) {
                const int r = wr * 64 + m * 16 + fr;
                const int pb = (r << 7) | ((kk * 64 + fq * 16) ^ ((r & 7) << 4));
                af[m] = *(const s8v*)(sA_ + pb);
            }
#pragma unroll
            for (int n = 0; n < 4; ++n) {
                const int r = wc * 64 + n * 16 + fr;
                const int pb = (r << 7) | ((kk * 64 + fq * 16) ^ ((r & 7) << 4));
                bfv[n] = *(const s8v*)(sB_ + pb);
            }
#pragma unroll
            for (int m = 0; m < 4; ++m)
#pragma unroll
                for (int n = 0; n < 4; ++n)
                    acc[m][n] = __builtin_amdgcn_mfma_f32_16x16x32_bf16(
                        af[m], bfv[n], acc[m][n], 0, 0, 0);
        }
    };

    STAGE(0, 0);
    asm volatile("s_waitcnt vmcnt(0)" ::: "memory");
    __syncthreads();
    int cur = 0;
    for (int t = 0; t < 3; ++t) {
        STAGE(cur ^ 1, (size_t)(t + 1) * 128);
        COMPUTE(cur);
        asm volatile("s_waitcnt vmcnt(0)" ::: "memory");
        __syncthreads();
        cur ^= 1;
    }
    COMPUTE(cur);

    const int row0L = wr * 64 + fq * 4;
    const int col0L = wc * 64 + fr;
    const bool diag = (xb == yb);
    bf16* Sb = S + (size_t)b * (size_t)N * N;
    char* smT = smb;

    int cmv[4];
#pragma unroll
    for (int n = 0; n < 4; ++n)
        cmv[n] = mask[(size_t)b * N + bn + col0L + n * 16];
    float cs[4] = {0.f, 0.f, 0.f, 0.f};

#pragma unroll
    for (int m = 0; m < 4; ++m) {
        int rmv[4];
#pragma unroll
        for (int r = 0; r < 4; ++r)
            rmv[r] = mask[(size_t)b * N + bm + row0L + m * 16 + r];
        float rs[4] = {0.f, 0.f, 0.f, 0.f};
#pragma unroll
        for (int n = 0; n < 4; ++n) {
            const int colL = col0L + n * 16;
            ushort4 u4;
#pragma unroll
            for (int r = 0; r < 4; ++r) {
                const float x = sigm(acc[m][n][r]);
                Sb[(size_t)(bm + row0L + m * 16 + r) * N + bn + colL] =
                    __float2bfloat16(x);
                if (cmv[n]) rs[r] += x;
                if (rmv[r]) cs[n] += x;
                ((unsigned short*)&u4)[r] = f2b(x);
            }
            if (!diag) {
                const int rowb = (row0L + m * 16) * 2;
                *(ushort4*)(smT + colL * 256 + (rowb ^ ((colL & 15) << 4))) = u4;
            }
        }
#pragma unroll
        for (int off = 1; off < 16; off <<= 1)
#pragma unroll
            for (int r = 0; r < 4; ++r) rs[r] += __shfl_xor(rs[r], off);
        if (fr == 0) {
#pragma unroll
            for (int r = 0; r < 4; ++r)
                part[((size_t)b * N + bm + row0L + m * 16 + r) * 32 +
                     yb * 2 + wc] = rs[r];
        }
    }

    if (!diag) {
#pragma unroll
        for (int n = 0; n < 4; ++n) {
            cs[n] += __shfl_xor(cs[n], 16);
            cs[n] += __shfl_xor(cs[n], 32);
        }
        if (fq == 0) {
#pragma unroll
            for (int n = 0; n < 4; ++n)
                part[((size_t)b * N + bn + wc * 64 + n * 16 + fr) * 32 +
                     xb * 2 + wr] = cs[n];
        }
        __syncthreads();
#pragma unroll
        for (int it = 0; it < 8; ++it) {
            const int cL = it * 16 + (tid >> 4);
            const int q8 = tid & 15;
            const s8v v = *(const s8v*)(smT + cL * 256 +
                                        ((q8 * 16) ^ ((cL & 15) << 4)));
            *(s8v*)&Sb[(size_t)(bn + cL) * N + bm + q8 * 8] = v;
        }
    }
}

// ---------------------------------------------------------------------------
// Final symmetric GEMM: out[b] = pairmask(sigmoid(P P^T)), f32, upper
// triangle of 128x128 tiles; off-diag emits transpose via LDS (R7-proven).
// ---------------------------------------------------------------------------
__global__ __launch_bounds__(256)
void gemm_tri(const bf16* __restrict__ Pm, float* __restrict__ C,
              const int* __restrict__ mask)
{
    constexpr int K = 256, N = 2048;
    constexpr int TILEB = 256 * 128;
    __shared__ char smb[2 * TILEB];

    const int id = blockIdx.x;
    const int swz = (id & 7) * 136 + (id >> 3);
    const int b = swz / 136;
    const int tri = swz - b * 136;
    int yb = (int)((sqrtf(8.0f * (float)tri + 1.0f) - 1.0f) * 0.5f);
    while ((yb + 1) * (yb + 2) / 2 <= tri) ++yb;
    while (yb * (yb + 1) / 2 > tri) --yb;
    const int xb = tri - yb * (yb + 1) / 2;
    const int bm = xb * 128, bn = yb * 128;

    const char* Ab = (const char*)(Pm + (size_t)b * N * K);
    const int tid = threadIdx.x;
    const int lane = tid & 63;
    const int wv = tid >> 6;
    const int wr = wv >> 1, wc = wv & 1;
    const int fr = lane & 15, fq = lane >> 4;
    const size_t lda = (size_t)K * 2;

    size_t aOff[4], bOff[4];
    int ldsO[4];
#pragma unroll
    for (int i = 0; i < 4; ++i) {
        const int local = i * 4096 + wv * 1024;
        const int myOff = local + lane * 16;
        const int row = myOff >> 7;
        const int lc = (myOff & 127) ^ ((row & 7) << 4);
        ldsO[i] = local;
        aOff[i] = (size_t)(bm + row) * lda + lc;
        bOff[i] = (size_t)(bn + row) * lda + lc;
    }

    f32x4 acc[4][4];
#pragma unroll
    for (int m = 0; m < 4; ++m)
#pragma unroll
        for (int n = 0; n < 4; ++n)
            acc[m][n] = (f32x4){0.f, 0.f, 0.f, 0.f};

    auto STAGE = [&](int buf, size_t kb) {
        char* base = smb + buf * TILEB;
#pragma unroll
        for (int i = 0; i < 4; ++i) {
            gload16(Ab + aOff[i] + kb, base + ldsO[i]);
            gload16(Ab + bOff[i] + kb, base + 16384 + ldsO[i]);
        }
    };

    auto COMPUTE = [&](int buf) {
        const char* sA_ = smb + buf * TILEB;
        const char* sB_ = sA_ + 16384;
#pragma unroll
        for (int kk = 0; kk < 2; ++kk) {
            s8v af[4], bfv[4];
#pragma unroll
            for (int m = 0; m < 4; ++m) {
                const int r = wr * 64 + m * 16 + fr;
                const int pb = (r << 7) | ((kk * 64 + fq * 16) ^ ((r & 7) << 4));
                af[m] = *(const s8v*)(sA_ + pb);
            }
#pragma unroll
            for (int n = 0; n < 4; ++n) {
                const int r = wc * 64 + n * 16 + fr;
                const int pb = (r << 7) | ((kk * 64 + fq * 16) ^ ((r & 7) << 4));
                bfv[n] = *(const s8v*)(sB_ + pb);
            }
#pragma unroll
            for (int m = 0; m < 4; ++m)
#pragma unroll
                for (int n = 0; n < 4; ++n)
                    acc[m][n] = __builtin_amdgcn_mfma_f32_16x16x32_bf16(
                        af[m], bfv[n], acc[m][n], 0, 0, 0);
        }
    };

    STAGE(0, 0);
    asm volatile("s_waitcnt vmcnt(0)" ::: "memory");
    __syncthreads();
    int cur = 0;
    for (int t = 0; t < 3; ++t) {
        STAGE(cur ^ 1, (size_t)(t + 1) * 128);
        COMPUTE(cur);
        asm volatile("s_waitcnt vmcnt(0)" ::: "memory");
        __syncthreads();
        cur ^= 1;
    }
    COMPUTE(cur);
    __syncthreads();

    const int row0L = wr * 64 + fq * 4;
    const int col0L = wc * 64 + fr;
    const bool diag = (xb == yb);
    float4* ft = (float4*)smb;

    int cmv[4];
#pragma unroll
    for (int n = 0; n < 4; ++n)
        cmv[n] = mask[(size_t)b * N + bn + col0L + n * 16];
#pragma unroll
    for (int m = 0; m < 4; ++m) {
        int rmv[4];
#pragma unroll
        for (int r = 0; r < 4; ++r)
            rmv[r] = mask[(size_t)b * N + bm + row0L + m * 16 + r];
#pragma unroll
        for (int n = 0; n < 4; ++n) {
            float vv[4];
#pragma unroll
            for (int r = 0; r < 4; ++r)
                vv[r] = (rmv[r] & cmv[n]) ? sigm(acc[m][n][r]) : 0.0f;
#pragma unroll
            for (int r = 0; r < 4; ++r)
                C[(size_t)b * N * N +
                  (size_t)(bm + row0L + m * 16 + r) * N + bn + col0L + n * 16] = vv[r];
            const int colL = col0L + n * 16;
            const int qd = (row0L + m * 16) >> 2;
            ft[colL * 32 + (qd ^ (colL & 31))] =
                make_float4(vv[0], vv[1], vv[2], vv[3]);
        }
    }
    if (!diag) {
        __syncthreads();
#pragma unroll 4
        for (int it = 0; it < 16; ++it) {
            const int cL = it * 8 + (tid >> 5);
            const int qd = tid & 31;
            const float4 v4 = ft[cL * 32 + (qd ^ (cL & 31))];
            *(float4*)&C[(size_t)b * N * N +
                         (size_t)(bn + cL) * N + bm + qd * 4] = v4;
        }
    }
}

// ---------------------------------------------------------------------------
// blocks [0,4096): row-normalize X -> Xn (bf16) + rnorm. One wave per row.
// blocks [4096,4352): transpose W1,W2 to bf16.
// ---------------------------------------------------------------------------
__global__ __launch_bounds__(256)
void xn_kernel(const float* __restrict__ X, bf16* __restrict__ Xn,
               float* __restrict__ rnorm,
               const float* __restrict__ W1, const float* __restrict__ W2,
               bf16* __restrict__ W1t, bf16* __restrict__ W2t)
{
    if (blockIdx.x >= 4096) {
        const int idx = (blockIdx.x - 4096) * 256 + threadIdx.x;
        const int h = idx & 255, d = idx >> 8;
        W1t[h * 256 + d] = __float2bfloat16(W1[idx]);
        W2t[h * 256 + d] = __float2bfloat16(W2[idx]);
        return;
    }
    const int lane = threadIdx.x & 63;
    const size_t row = (size_t)blockIdx.x * 4 + (threadIdx.x >> 6);
    const float4 v = *(const float4*)&X[row * 256 + lane * 4];
    float ss = v.x * v.x + v.y * v.y + v.z * v.z + v.w * v.w;
#pragma unroll
    for (int o = 32; o; o >>= 1) ss += __shfl_xor(ss, o);
    const float nrm = fmaxf(sqrtf(ss), 1e-12f);
    const float inv = 1.0f / nrm;
    ushort4 o4;
    o4.x = f2b(v.x * inv); o4.y = f2b(v.y * inv);
    o4.z = f2b(v.z * inv); o4.w = f2b(v.w * inv);
    *(ushort4*)&Xn[row * 256 + lane * 4] = o4;
    if (lane == 0) rnorm[row] = nrm;
}

// ---------------------------------------------------------------------------
// Fused degree-finalize + Y/Yt build. Per block: 64 rows x 64 cols of Xn.
// ---------------------------------------------------------------------------
__global__ __launch_bounds__(256)
void ytY_kernel(const bf16* __restrict__ Xn, const float* __restrict__ rnorm,
                const float* __restrict__ part, const int* __restrict__ mask,
                float* __restrict__ dvl, bf16* __restrict__ Y,
                bf16* __restrict__ Yt)
{
    __shared__ float tile[64][65];
    __shared__ float dsh[64];
    const int b = blockIdx.z;
    const int m0 = blockIdx.x * 64, d0 = blockIdx.y * 64;
    const int t = threadIdx.x;

    if (t < 64) {
        const size_t grow = (size_t)b * 2048 + m0 + t;
        float s = 0.f;
#pragma unroll 8
        for (int i = 0; i < 32; ++i) s += part[grow * 32 + i];
        const float deg = mask[grow] ? (s + 1.0f) : 0.0f;
        const float dv = rsqrtf(fmaxf(deg, 1e-6f));
        dvl[grow] = dv;
        dsh[t] = mask[grow] ? dv * rnorm[grow] : 0.0f;
    }
    __syncthreads();

    const bf16* Xb = Xn + (size_t)b * 2048 * 256;
    const int rr = t >> 3;
    const int c8 = (t & 7) * 8;
#pragma unroll
    for (int i = 0; i < 2; ++i) {
        const int m = rr + i * 32;
        const int gm = m0 + m;
        const float s = dsh[m];
        const s8v v = *(const s8v*)&Xb[(size_t)gm * 256 + d0 + c8];
        ushort4 lo, hi;
        float f[8];
#pragma unroll
        for (int j = 0; j < 8; ++j) {
            f[j] = b2f((unsigned short)v[j]) * s;
            tile[m][c8 + j] = f[j];
        }
        lo.x = f2b(f[0]); lo.y = f2b(f[1]); lo.z = f2b(f[2]); lo.w = f2b(f[3]);
        hi.x = f2b(f[4]); hi.y = f2b(f[5]); hi.z = f2b(f[6]); hi.w = f2b(f[7]);
        bf16* yrow = Y + (size_t)b * 2048 * 256 + (size_t)gm * 256 + d0 + c8;
        *(ushort4*)yrow = lo;
        *(ushort4*)(yrow + 4) = hi;
    }
    __syncthreads();
    bf16* Yb = Yt + (size_t)b * 256 * 2048;
    const int dd = t >> 3;
    const int m8 = (t & 7) * 8;
#pragma unroll
    for (int i = 0; i < 2; ++i) {
        const int d = dd + i * 32;
        ushort4 lo, hi;
        lo.x = f2b(tile[m8 + 0][d]); lo.y = f2b(tile[m8 + 1][d]);
        lo.z = f2b(tile[m8 + 2][d]); lo.w = f2b(tile[m8 + 3][d]);
        hi.x = f2b(tile[m8 + 4][d]); hi.y = f2b(tile[m8 + 5][d]);
        hi.z = f2b(tile[m8 + 6][d]); hi.w = f2b(tile[m8 + 7][d]);
        bf16* yt = Yb + (size_t)(d0 + d) * 2048 + m0 + m8;
        *(ushort4*)yt = lo;
        *(ushort4*)(yt + 4) = hi;
    }
}

extern "C" void kernel_launch(void* const* d_in, const int* in_sizes, int n_in,
                              void* d_out, int out_size, void* d_ws, size_t ws_size,
                              hipStream_t stream)
{
    (void)in_sizes; (void)n_in; (void)out_size; (void)ws_size;
    const float* X  = (const float*)d_in[0];
    const int*  msk = (const int*)d_in[1];
    const float* W1 = (const float*)d_in[2];
    const float* b1 = (const float*)d_in[3];
    const float* W2 = (const float*)d_in[4];
    const float* b2 = (const float*)d_in[5];

    // scratch inside d_out (134,217,728 B), all dead before the final GEMM:
    char* O = (char*)d_out;
    bf16* S    = (bf16*)(O);                 // 67,108,864 B  [8][2048][2048]
    bf16* Xn   = (bf16*)(O + 67108864);      //  8,388,608 B  [8][2048][256]
    bf16* Yt   = (bf16*)(O + 75497472);      //  8,388,608 B  [8][256][2048]
    bf16* agg  = (bf16*)(O + 83886080);      //  8,388,608 B  [8][2048][256]
    float* dvl = (float*)(O + 100663296);    //     65,536 B  [8][2048]
    bf16* W1t  = (bf16*)(O + 100728832);     //    131,072 B
    bf16* W2t  = (bf16*)(O + 100859904);     //    131,072 B
    float* part= (float*)(O + 100990976);    //  2,097,152 B  [8][2048][32]
    bf16* Y    = (bf16*)(O + 103088128);     //  8,388,608 B  [8][2048][256]
    float* rnm = (float*)(O + 111476736);    //     65,536 B  [8][2048]
    bf16* P    = (bf16*)d_ws;                //  8,388,608 B  (survives final GEMM)

    xn_kernel<<<4352, 256, 0, stream>>>(X, Xn, rnm, W1, W2, W1t, W2t);

    // S = sigmoid(Xn Xn^T) bf16, triangular + transpose emit + degree partials
    gemm_stri<<<1088, 256, 0, stream>>>(Xn, S, msk, part);

    // fused fin_deg + Y/Yt build
    ytY_kernel<<<dim3(32, 4, 8), 256, 0, stream>>>(
        Xn, rnm, part, msk, dvl, Y, Yt);

    // agg = m_i ? d_i*(S@Y + Y_i) : 0, bf16  (128x64 tiles, XCD chunk = batch)
    gemm_bt<128, 64, 1><<<512, 256, 0, stream>>>(
        S, Yt, agg, 2048, 256, 2048,
        (size_t)2048 * 2048, (size_t)256 * 2048, (size_t)2048 * 256,
        Y, dvl, msk, 16, 4);

    // P = relu(agg @ W1 + b1) @ W2 + b2, fused MLP (Hf stays in LDS)
    mlp_fused<<<256, 512, 0, stream>>>(agg, W1t, b1, W2t, b2, P);

    // out = pairmask(sigmoid(P P^T)), f32, triangular + transposed emit
    gemm_tri<<<1088, 256, 0, stream>>>(P, (float*)d_out, msk);
}